// Round 6
// baseline (250.732 us; speedup 1.0000x reference)
//
#include <hip/hip_runtime.h>
#include <hip/hip_bf16.h>
#include <math.h>

#define EPS 1e-8f
#define BB 32
#define SS 64
#define HH 200
#define LL 20
#define KP 224    // K padded to 7*32
#define KST 232   // LDS tile row stride in bf16 elems (2-way-free banking, 16B aligned)

typedef short bf16x8 __attribute__((ext_vector_type(8)));   // 8 bf16 in 4 VGPRs
typedef float f32x4 __attribute__((ext_vector_type(4)));

// ws layout (floats):
// att 262144 | n2arr 8192 | wn 163840 | w2pt 8000 | w2t 24000 | meanv 1638400 | maxv 1638400

// ---------------------------------------------------------------- prep: squared weights + plain norms
__global__ void prep_kernel(const float* __restrict__ conp, const float* __restrict__ conh,
                            const float* __restrict__ w1, const float* __restrict__ w2,
                            const float* __restrict__ w3, const float* __restrict__ w4,
                            const float* __restrict__ w5, const float* __restrict__ w6,
                            const float* __restrict__ w7, const float* __restrict__ w8,
                            float* __restrict__ w2pt, float* __restrict__ w2t,
                            float* __restrict__ n2arr) {
    if (blockIdx.x < 32) {
        int idx = blockIdx.x * 256 + threadIdx.x;
        if (idx >= 2 * LL * HH) return;
        int dir = idx / (LL * HH);
        int r = idx % (LL * HH);
        int l = r / HH, h = r % HH;
        int h2 = h >> 1, comp = h & 1;
        float v = (dir == 0 ? w3 : w4)[l * HH + h];
        w2pt[(dir * 100 + h2) * 40 + l * 2 + comp] = v * v;   // [dir][h2][l][2]
        const float* wa = dir ? w2 : w1;
        const float* wb = dir ? w6 : w5;
        const float* wc = dir ? w8 : w7;
        float ua = wa[l * HH + h], ub = wb[l * HH + h], uc = wc[l * HH + h];
        w2t[((dir * 3 + 0) * 100 + h2) * 40 + l * 2 + comp] = ua * ua;
        w2t[((dir * 3 + 1) * 100 + h2) * 40 + l * 2 + comp] = ub * ub;
        w2t[((dir * 3 + 2) * 100 + h2) * 40 + l * 2 + comp] = uc * uc;
    } else {
        int t = threadIdx.x;
        int wave = t >> 6, lane = t & 63;
        int e = (blockIdx.x - 32) * 4 + wave;
        int s = e & 63, b = (e >> 6) & 31, sd = e >> 11;
        int dir = sd & 1, side = sd >> 1;
        const float* v = (side ? conh : conp) + (b * SS + s) * (2 * HH) + dir * HH;
        float val = 0.f;
        if (lane < 50) {
            float4 f = ((const float4*)v)[lane];
            val = f.x * f.x + f.y * f.y + f.z * f.z + f.w * f.w;
        }
#pragma unroll
        for (int off = 32; off >= 1; off >>= 1) val += __shfl_xor(val, off, 64);
        if (lane == 0) n2arr[e] = sqrtf(val);
    }
}

// ---------------------------------------------------------------- attention matrix
__global__ void att_kernel(const float* __restrict__ conp, const float* __restrict__ conh,
                           const float* __restrict__ n2arr, float* __restrict__ att) {
    int blk = blockIdx.x;
    int p = blk & 63, b = (blk >> 6) & 31, dir = blk >> 11;
    int q = threadIdx.x;
    __shared__ float4 pvL[50];
    const float* pv = conp + (b * SS + p) * (2 * HH) + dir * HH;
    if (q < 50) pvL[q] = ((const float4*)pv)[q];
    __syncthreads();
    const float4* hv = (const float4*)(conh + (b * SS + q) * (2 * HH) + dir * HH);
    float dot = 0.f;
    for (int j = 0; j < 50; ++j) {
        float4 a = pvL[j]; float4 c = hv[j];
        dot = fmaf(a.x, c.x, dot); dot = fmaf(a.y, c.y, dot);
        dot = fmaf(a.z, c.z, dot); dot = fmaf(a.w, c.w, dot);
    }
    float n1 = n2arr[((0 * 2 + dir) * BB + b) * SS + p];
    float n2 = n2arr[((1 * 2 + dir) * BB + b) * SS + q];
    att[blk * SS + q] = dot / fmaxf(n1 * n2, EPS);
}

// ---------------------------------------------------------------- att-mean & att-max vectors
__global__ void attvec_kernel(const float* __restrict__ conp, const float* __restrict__ conh,
                              const float* __restrict__ att,
                              float* __restrict__ meanv, float* __restrict__ maxv) {
    int blk = blockIdx.x;
    int ht = blk & 7, b = (blk >> 3) & 31, sd = blk >> 8;
    int dir = sd & 1, side = sd >> 1;
    int t = threadIdx.x;
    __shared__ float attL[SS * 65];
    __shared__ float oppL[SS * 26];
    const float* abase = att + (dir * BB + b) * SS * SS;
    for (int e = t; e < SS * SS; e += 256) {
        int r = e >> 6, c = e & 63;
        float v = abase[e];
        if (side == 0) attL[r * 65 + c] = v;
        else           attL[c * 65 + r] = v;
    }
    const float* opp = (side == 0 ? conh : conp);
    for (int e = t; e < SS * 25; e += 256) {
        int k = e / 25, j = e - k * 25;
        oppL[k * 26 + j] = opp[(b * SS + k) * (2 * HH) + dir * HH + ht * 25 + j];
    }
    __syncthreads();
    int s = t >> 2, c3 = t & 3;
    int j0 = c3 * 7;
    float ms[7], mx[7];
#pragma unroll
    for (int i = 0; i < 7; ++i) { ms[i] = 0.f; mx[i] = -INFINITY; }
    float dn = 0.f;
    for (int k = 0; k < SS; ++k) {
        float a = attL[s * 65 + k];
        dn += a;
        int base = k * 26 + j0;
#pragma unroll
        for (int i = 0; i < 7; ++i) {
            if (j0 + i < 25) {
                float tt = a * oppL[base + i];
                ms[i] += tt;
                mx[i] = fmaxf(mx[i], tt);
            }
        }
    }
    float dd = fmaxf(dn, EPS);
    int obase = (((side * 2 + dir) * BB + b) * SS + s) * HH + ht * 25 + j0;
#pragma unroll
    for (int i = 0; i < 7; ++i) {
        if (j0 + i < 25) {
            meanv[obase + i] = ms[i] / dd;
            maxv[obase + i]  = mx[i];
        }
    }
}

// ---------------------------------------------------------------- mp_match (full/mean/max) + wn
__global__ void match_kernel(const float* __restrict__ conp, const float* __restrict__ conh,
                             const float* __restrict__ meanv, const float* __restrict__ maxv,
                             const float* __restrict__ w2t, const float* __restrict__ w2pt,
                             float* __restrict__ out, float* __restrict__ wn) {
    int blk = blockIdx.x;
    int s = blk & 63, b = (blk >> 6) & 31, sd = blk >> 11;
    int dir = sd & 1, side = sd >> 1;
    int t = threadIdx.x;
    __shared__ __align__(16) float x2L[HH];
    __shared__ __align__(16) float xyL[3][HH];
    __shared__ __align__(16) float y2L[3][HH];
    const float* v1 = (side == 0 ? conp : conh) + (b * SS + s) * (2 * HH) + dir * HH;
    const float* opp = (side == 0 ? conh : conp);
    int fidx = (dir == 0) ? (SS - 1) : 0;
    const float* fv = opp + (b * SS + fidx) * (2 * HH) + dir * HH;
    const float* mv = meanv + (((side * 2 + dir) * BB + b) * SS + s) * HH;
    const float* xv = maxv  + (((side * 2 + dir) * BB + b) * SS + s) * HH;
    for (int h = t; h < HH; h += 64) {
        float x = v1[h];
        x2L[h] = x * x;
        float y0 = fv[h], y1 = mv[h], y2v = xv[h];
        xyL[0][h] = x * y0;  y2L[0][h] = y0 * y0;
        xyL[1][h] = x * y1;  y2L[1][h] = y1 * y1;
        xyL[2][h] = x * y2v; y2L[2][h] = y2v * y2v;
    }
    __syncthreads();
    if (t < 60) {
        int m = t / 20, l = t - m * 20;
        const float* wt = w2t + (dir * 3 + m) * 4000 + l * 2;
        float d0 = 0, d1 = 0, a0 = 0, a1 = 0, b0 = 0, b1 = 0;
        for (int h2 = 0; h2 < 100; ++h2) {
            float2 w  = *(const float2*)(wt + h2 * 40);
            float2 xy = *(const float2*)&xyL[m][h2 * 2];
            float2 x2 = *(const float2*)&x2L[h2 * 2];
            float2 yy = *(const float2*)&y2L[m][h2 * 2];
            d0 = fmaf(xy.x, w.x, d0); d1 = fmaf(xy.y, w.y, d1);
            a0 = fmaf(x2.x, w.x, a0); a1 = fmaf(x2.y, w.y, a1);
            b0 = fmaf(yy.x, w.x, b0); b1 = fmaf(yy.y, w.y, b1);
        }
        float d = d0 + d1, a = a0 + a1, bb2 = b0 + b1;
        float cosv = d / fmaxf(sqrtf(a * bb2), EPS);
        int chunk = (m == 0) ? 0 : (m == 1) ? 40 : 60;
        out[side * (BB * SS * 160) + (b * SS + s) * 160 + dir * 80 + chunk + l] = cosv;
    }
    if (t < 20) {
        const float* pw = w2pt + dir * 4000 + t * 2;
        float n0 = 0, n1v = 0;
        for (int h2 = 0; h2 < 100; ++h2) {
            float2 w  = *(const float2*)(pw + h2 * 40);
            float2 x2 = *(const float2*)&x2L[h2 * 2];
            n0  = fmaf(x2.x, w.x, n0);
            n1v = fmaf(x2.y, w.y, n1v);
        }
        wn[blk * LL + t] = sqrtf(n0 + n1v);
    }
}

// ---------------------------------------------------------------- pairwise via bf16 MFMA
// blk = ((dir*BB+b)*LL + l) ; 4 waves; wave w owns row strip 16w; 4 col tiles each.
// dot_l = (A .* w_l) @ (B .* w_l)^T via 16x16x32 bf16 MFMA; cosine + row/col max fused.
__global__ __launch_bounds__(256) void pairmfma_kernel(
        const float* __restrict__ conp, const float* __restrict__ conh,
        const float* __restrict__ w3, const float* __restrict__ w4,
        const float* __restrict__ wn, float* __restrict__ out) {
    int blk = blockIdx.x;
    int l = blk % LL; int db = blk / LL; int b = db & 31; int dir = db >> 5;
    int t = threadIdx.x;
    __shared__ __hip_bfloat16 AT[64 * KST];
    __shared__ __hip_bfloat16 BT[64 * KST];
    __shared__ float cmL[4 * 64];

    const float* wrow = (dir ? w4 : w3) + l * HH;
    const float* Ag = conp + dir * HH;
    const float* Bg = conh + dir * HH;
    for (int e = t; e < 64 * KP; e += 256) {
        int m = e / KP, k = e - m * KP;
        float wv = 0.f, av = 0.f, bv = 0.f;
        if (k < HH) {
            wv = wrow[k];
            av = Ag[(b * SS + m) * (2 * HH) + k];
            bv = Bg[(b * SS + m) * (2 * HH) + k];
        }
        AT[m * KST + k] = __float2bfloat16(av * wv);
        BT[m * KST + k] = __float2bfloat16(bv * wv);
    }
    __syncthreads();

    int wv_ = __builtin_amdgcn_readfirstlane(t >> 6);
    int lane = t & 63;
    int q = lane >> 4, c = lane & 15;
    int m0 = wv_ * 16;

    f32x4 acc[4];
#pragma unroll
    for (int ct = 0; ct < 4; ++ct) acc[ct] = (f32x4){0.f, 0.f, 0.f, 0.f};

    for (int ks = 0; ks < 7; ++ks) {
        int kb = ks * 32 + q * 8;
        bf16x8 af = *(const bf16x8*)&AT[(m0 + c) * KST + kb];
#pragma unroll
        for (int ct = 0; ct < 4; ++ct) {
            bf16x8 bf_ = *(const bf16x8*)&BT[(ct * 16 + c) * KST + kb];
            acc[ct] = __builtin_amdgcn_mfma_f32_16x16x32_bf16(af, bf_, acc[ct], 0, 0, 0);
        }
    }

    // norms (fp32, from match_kernel's wn)
    float na[4], nb[4];
#pragma unroll
    for (int r = 0; r < 4; ++r) {
        int i = m0 + q * 4 + r;
        na[r] = wn[(((0 * 2 + dir) * BB + b) * SS + i) * LL + l];
    }
#pragma unroll
    for (int ct = 0; ct < 4; ++ct) {
        int j = ct * 16 + c;
        nb[ct] = wn[(((1 * 2 + dir) * BB + b) * SS + j) * LL + l];
    }

    float rowm[4] = {-INFINITY, -INFINITY, -INFINITY, -INFINITY};
    float colm[4] = {-INFINITY, -INFINITY, -INFINITY, -INFINITY};
#pragma unroll
    for (int ct = 0; ct < 4; ++ct) {
#pragma unroll
        for (int r = 0; r < 4; ++r) {
            float cv = acc[ct][r] / fmaxf(na[r] * nb[ct], EPS);
            rowm[r] = fmaxf(rowm[r], cv);
            colm[ct] = fmaxf(colm[ct], cv);
        }
    }

    // row-max: reduce over the 16 lanes (cols) sharing this q-group
#pragma unroll
    for (int r = 0; r < 4; ++r) {
        float v = rowm[r];
        v = fmaxf(v, __shfl_xor(v, 1, 64));
        v = fmaxf(v, __shfl_xor(v, 2, 64));
        v = fmaxf(v, __shfl_xor(v, 4, 64));
        v = fmaxf(v, __shfl_xor(v, 8, 64));
        rowm[r] = v;
    }
    if (c == 0) {
#pragma unroll
        for (int r = 0; r < 4; ++r) {
            int i = m0 + q * 4 + r;
            out[(b * SS + i) * 160 + dir * 80 + 20 + l] = rowm[r];   // mv_p chunk
        }
    }

    // col-max: reduce over q groups, then across 4 waves via LDS
#pragma unroll
    for (int ct = 0; ct < 4; ++ct) {
        float v = colm[ct];
        v = fmaxf(v, __shfl_xor(v, 16, 64));
        v = fmaxf(v, __shfl_xor(v, 32, 64));
        colm[ct] = v;
    }
    if (q == 0) {
#pragma unroll
        for (int ct = 0; ct < 4; ++ct) cmL[wv_ * 64 + ct * 16 + c] = colm[ct];
    }
    __syncthreads();
    if (t < 64) {
        float m = fmaxf(fmaxf(cmL[t], cmL[64 + t]), fmaxf(cmL[128 + t], cmL[192 + t]));
        out[BB * SS * 160 + (b * SS + t) * 160 + dir * 80 + 20 + l] = m;  // mv_h chunk
    }
}

extern "C" void kernel_launch(void* const* d_in, const int* in_sizes, int n_in,
                              void* d_out, int out_size, void* d_ws, size_t ws_size,
                              hipStream_t stream) {
    const float* conp = (const float*)d_in[0];
    const float* conh = (const float*)d_in[1];
    const float* w1 = (const float*)d_in[2];
    const float* w2 = (const float*)d_in[3];
    const float* w3 = (const float*)d_in[4];
    const float* w4 = (const float*)d_in[5];
    const float* w5 = (const float*)d_in[6];
    const float* w6 = (const float*)d_in[7];
    const float* w7 = (const float*)d_in[8];
    const float* w8 = (const float*)d_in[9];
    float* out = (float*)d_out;
    float* ws  = (float*)d_ws;

    float* att    = ws;                        // 262144
    float* n2arr  = att + 2 * BB * SS * SS;    // 8192
    float* wn     = n2arr + 4 * BB * SS;       // 163840
    float* w2pt   = wn + 4 * BB * SS * LL;     // 8000
    float* w2t    = w2pt + 2 * LL * HH;        // 24000
    float* meanv  = w2t + 6 * LL * HH;         // 1638400
    float* maxv   = meanv + 4 * BB * SS * HH;  // 1638400

    prep_kernel<<<32 + 4 * BB * SS / 4, 256, 0, stream>>>(conp, conh, w1, w2, w3, w4, w5, w6,
                                                          w7, w8, w2pt, w2t, n2arr);
    att_kernel<<<2 * BB * SS, 64, 0, stream>>>(conp, conh, n2arr, att);
    attvec_kernel<<<4 * BB * 8, 256, 0, stream>>>(conp, conh, att, meanv, maxv);
    match_kernel<<<4 * BB * SS, 64, 0, stream>>>(conp, conh, meanv, maxv, w2t, w2pt, out, wn);
    pairmfma_kernel<<<2 * BB * LL, 256, 0, stream>>>(conp, conh, w3, w4, wn, out);
}

// Round 7
// 200.467 us; speedup vs baseline: 1.2507x; 1.2507x over previous
//
#include <hip/hip_runtime.h>
#include <hip/hip_bf16.h>
#include <math.h>

#define EPS 1e-8f
#define BB 32
#define SS 64
#define HH 200
#define LL 20
#define KP 224    // K padded to 7*32
#define KST 232   // LDS tile row stride in bf16 elems (232*2B=464B: 2-way-free banking, 16B aligned)

typedef short bf16x8 __attribute__((ext_vector_type(8)));   // 8 bf16 in 4 VGPRs
typedef float f32x4 __attribute__((ext_vector_type(4)));

// ws layout (floats):
// att 262144 | n2arr 8192 | wn 163840 | w2pt 8000 | w2t 24000 | meanv 1638400 | maxv 1638400

// ---------------------------------------------------------------- prep: squared weights + plain norms
__global__ void prep_kernel(const float* __restrict__ conp, const float* __restrict__ conh,
                            const float* __restrict__ w1, const float* __restrict__ w2,
                            const float* __restrict__ w3, const float* __restrict__ w4,
                            const float* __restrict__ w5, const float* __restrict__ w6,
                            const float* __restrict__ w7, const float* __restrict__ w8,
                            float* __restrict__ w2pt, float* __restrict__ w2t,
                            float* __restrict__ n2arr) {
    if (blockIdx.x < 32) {
        int idx = blockIdx.x * 256 + threadIdx.x;
        if (idx >= 2 * LL * HH) return;
        int dir = idx / (LL * HH);
        int r = idx % (LL * HH);
        int l = r / HH, h = r % HH;
        int h2 = h >> 1, comp = h & 1;
        float v = (dir == 0 ? w3 : w4)[l * HH + h];
        w2pt[(dir * 100 + h2) * 40 + l * 2 + comp] = v * v;   // [dir][h2][l][2]
        const float* wa = dir ? w2 : w1;
        const float* wb = dir ? w6 : w5;
        const float* wc = dir ? w8 : w7;
        float ua = wa[l * HH + h], ub = wb[l * HH + h], uc = wc[l * HH + h];
        w2t[((dir * 3 + 0) * 100 + h2) * 40 + l * 2 + comp] = ua * ua;
        w2t[((dir * 3 + 1) * 100 + h2) * 40 + l * 2 + comp] = ub * ub;
        w2t[((dir * 3 + 2) * 100 + h2) * 40 + l * 2 + comp] = uc * uc;
    } else {
        int t = threadIdx.x;
        int wave = t >> 6, lane = t & 63;
        int e = (blockIdx.x - 32) * 4 + wave;
        int s = e & 63, b = (e >> 6) & 31, sd = e >> 11;
        int dir = sd & 1, side = sd >> 1;
        const float* v = (side ? conh : conp) + (b * SS + s) * (2 * HH) + dir * HH;
        float val = 0.f;
        if (lane < 50) {
            float4 f = ((const float4*)v)[lane];
            val = f.x * f.x + f.y * f.y + f.z * f.z + f.w * f.w;
        }
#pragma unroll
        for (int off = 32; off >= 1; off >>= 1) val += __shfl_xor(val, off, 64);
        if (lane == 0) n2arr[e] = sqrtf(val);
    }
}

// ---------------------------------------------------------------- attention matrix
__global__ void att_kernel(const float* __restrict__ conp, const float* __restrict__ conh,
                           const float* __restrict__ n2arr, float* __restrict__ att) {
    int blk = blockIdx.x;
    int p = blk & 63, b = (blk >> 6) & 31, dir = blk >> 11;
    int q = threadIdx.x;
    __shared__ float4 pvL[50];
    const float* pv = conp + (b * SS + p) * (2 * HH) + dir * HH;
    if (q < 50) pvL[q] = ((const float4*)pv)[q];
    __syncthreads();
    const float4* hv = (const float4*)(conh + (b * SS + q) * (2 * HH) + dir * HH);
    float dot = 0.f;
    for (int j = 0; j < 50; ++j) {
        float4 a = pvL[j]; float4 c = hv[j];
        dot = fmaf(a.x, c.x, dot); dot = fmaf(a.y, c.y, dot);
        dot = fmaf(a.z, c.z, dot); dot = fmaf(a.w, c.w, dot);
    }
    float n1 = n2arr[((0 * 2 + dir) * BB + b) * SS + p];
    float n2 = n2arr[((1 * 2 + dir) * BB + b) * SS + q];
    att[blk * SS + q] = dot / fmaxf(n1 * n2, EPS);
}

// ---------------------------------------------------------------- att-mean & att-max vectors
__global__ void attvec_kernel(const float* __restrict__ conp, const float* __restrict__ conh,
                              const float* __restrict__ att,
                              float* __restrict__ meanv, float* __restrict__ maxv) {
    int blk = blockIdx.x;
    int ht = blk & 7, b = (blk >> 3) & 31, sd = blk >> 8;
    int dir = sd & 1, side = sd >> 1;
    int t = threadIdx.x;
    __shared__ float attL[SS * 65];
    __shared__ float oppL[SS * 26];
    const float* abase = att + (dir * BB + b) * SS * SS;
    for (int e = t; e < SS * SS; e += 256) {
        int r = e >> 6, c = e & 63;
        float v = abase[e];
        if (side == 0) attL[r * 65 + c] = v;
        else           attL[c * 65 + r] = v;
    }
    const float* opp = (side == 0 ? conh : conp);
    for (int e = t; e < SS * 25; e += 256) {
        int k = e / 25, j = e - k * 25;
        oppL[k * 26 + j] = opp[(b * SS + k) * (2 * HH) + dir * HH + ht * 25 + j];
    }
    __syncthreads();
    int s = t >> 2, c3 = t & 3;
    int j0 = c3 * 7;
    float ms[7], mx[7];
#pragma unroll
    for (int i = 0; i < 7; ++i) { ms[i] = 0.f; mx[i] = -INFINITY; }
    float dn = 0.f;
    for (int k = 0; k < SS; ++k) {
        float a = attL[s * 65 + k];
        dn += a;
        int base = k * 26 + j0;
#pragma unroll
        for (int i = 0; i < 7; ++i) {
            if (j0 + i < 25) {
                float tt = a * oppL[base + i];
                ms[i] += tt;
                mx[i] = fmaxf(mx[i], tt);
            }
        }
    }
    float dd = fmaxf(dn, EPS);
    int obase = (((side * 2 + dir) * BB + b) * SS + s) * HH + ht * 25 + j0;
#pragma unroll
    for (int i = 0; i < 7; ++i) {
        if (j0 + i < 25) {
            meanv[obase + i] = ms[i] / dd;
            maxv[obase + i]  = mx[i];
        }
    }
}

// ---------------------------------------------------------------- mp_match (full/mean/max) + wn
__global__ void match_kernel(const float* __restrict__ conp, const float* __restrict__ conh,
                             const float* __restrict__ meanv, const float* __restrict__ maxv,
                             const float* __restrict__ w2t, const float* __restrict__ w2pt,
                             float* __restrict__ out, float* __restrict__ wn) {
    int blk = blockIdx.x;
    int s = blk & 63, b = (blk >> 6) & 31, sd = blk >> 11;
    int dir = sd & 1, side = sd >> 1;
    int t = threadIdx.x;
    __shared__ __align__(16) float x2L[HH];
    __shared__ __align__(16) float xyL[3][HH];
    __shared__ __align__(16) float y2L[3][HH];
    const float* v1 = (side == 0 ? conp : conh) + (b * SS + s) * (2 * HH) + dir * HH;
    const float* opp = (side == 0 ? conh : conp);
    int fidx = (dir == 0) ? (SS - 1) : 0;
    const float* fv = opp + (b * SS + fidx) * (2 * HH) + dir * HH;
    const float* mv = meanv + (((side * 2 + dir) * BB + b) * SS + s) * HH;
    const float* xv = maxv  + (((side * 2 + dir) * BB + b) * SS + s) * HH;
    for (int h = t; h < HH; h += 64) {
        float x = v1[h];
        x2L[h] = x * x;
        float y0 = fv[h], y1 = mv[h], y2v = xv[h];
        xyL[0][h] = x * y0;  y2L[0][h] = y0 * y0;
        xyL[1][h] = x * y1;  y2L[1][h] = y1 * y1;
        xyL[2][h] = x * y2v; y2L[2][h] = y2v * y2v;
    }
    __syncthreads();
    if (t < 60) {
        int m = t / 20, l = t - m * 20;
        const float* wt = w2t + (dir * 3 + m) * 4000 + l * 2;
        float d0 = 0, d1 = 0, a0 = 0, a1 = 0, b0 = 0, b1 = 0;
        for (int h2 = 0; h2 < 100; ++h2) {
            float2 w  = *(const float2*)(wt + h2 * 40);
            float2 xy = *(const float2*)&xyL[m][h2 * 2];
            float2 x2 = *(const float2*)&x2L[h2 * 2];
            float2 yy = *(const float2*)&y2L[m][h2 * 2];
            d0 = fmaf(xy.x, w.x, d0); d1 = fmaf(xy.y, w.y, d1);
            a0 = fmaf(x2.x, w.x, a0); a1 = fmaf(x2.y, w.y, a1);
            b0 = fmaf(yy.x, w.x, b0); b1 = fmaf(yy.y, w.y, b1);
        }
        float d = d0 + d1, a = a0 + a1, bb2 = b0 + b1;
        float cosv = d / fmaxf(sqrtf(a * bb2), EPS);
        int chunk = (m == 0) ? 0 : (m == 1) ? 40 : 60;
        out[side * (BB * SS * 160) + (b * SS + s) * 160 + dir * 80 + chunk + l] = cosv;
    }
    if (t < 20) {
        const float* pw = w2pt + dir * 4000 + t * 2;
        float n0 = 0, n1v = 0;
        for (int h2 = 0; h2 < 100; ++h2) {
            float2 w  = *(const float2*)(pw + h2 * 40);
            float2 x2 = *(const float2*)&x2L[h2 * 2];
            n0  = fmaf(x2.x, w.x, n0);
            n1v = fmaf(x2.y, w.y, n1v);
        }
        wn[blk * LL + t] = sqrtf(n0 + n1v);
    }
}

// ---------------------------------------------------------------- pairwise via bf16 MFMA
// blk = ((dir*BB+b)*LL + l) ; 4 waves; wave w owns row strip 16w; 4 col tiles each.
// Staging is 8-wide vectorized: float4 loads, packed bf16 cvt, ds_write_b128.
__global__ __launch_bounds__(256) void pairmfma_kernel(
        const float* __restrict__ conp, const float* __restrict__ conh,
        const float* __restrict__ w3, const float* __restrict__ w4,
        const float* __restrict__ wn, float* __restrict__ out) {
    int blk = blockIdx.x;
    int l = blk % LL; int db = blk / LL; int b = db & 31; int dir = db >> 5;
    int t = threadIdx.x;
    __shared__ __hip_bfloat16 AT[64 * KST];
    __shared__ __hip_bfloat16 BT[64 * KST];
    __shared__ float cmL[4 * 64];

    const float* wrow = (dir ? w4 : w3) + l * HH;
    const float* Ag = conp + dir * HH;
    const float* Bg = conh + dir * HH;

    // 8-wide staging: 64 rows x 28 chunks; chunks 25..27 (k>=200) are zero
    for (int e = t; e < 64 * 28; e += 256) {
        int m = e / 28, ck = e - m * 28;
        int k = ck * 8;
        __align__(16) __hip_bfloat16 at8[8];
        __align__(16) __hip_bfloat16 bt8[8];
        if (k < HH) {
            const float* ap = Ag + (b * SS + m) * (2 * HH) + k;
            const float* bp = Bg + (b * SS + m) * (2 * HH) + k;
            const float* wp = wrow + k;
            float4 a0 = *(const float4*)ap, a1 = *(const float4*)(ap + 4);
            float4 b0 = *(const float4*)bp, b1 = *(const float4*)(bp + 4);
            float4 w0 = *(const float4*)wp, w1 = *(const float4*)(wp + 4);
            at8[0] = __float2bfloat16(a0.x * w0.x); at8[1] = __float2bfloat16(a0.y * w0.y);
            at8[2] = __float2bfloat16(a0.z * w0.z); at8[3] = __float2bfloat16(a0.w * w0.w);
            at8[4] = __float2bfloat16(a1.x * w1.x); at8[5] = __float2bfloat16(a1.y * w1.y);
            at8[6] = __float2bfloat16(a1.z * w1.z); at8[7] = __float2bfloat16(a1.w * w1.w);
            bt8[0] = __float2bfloat16(b0.x * w0.x); bt8[1] = __float2bfloat16(b0.y * w0.y);
            bt8[2] = __float2bfloat16(b0.z * w0.z); bt8[3] = __float2bfloat16(b0.w * w0.w);
            bt8[4] = __float2bfloat16(b1.x * w1.x); bt8[5] = __float2bfloat16(b1.y * w1.y);
            bt8[6] = __float2bfloat16(b1.z * w1.z); bt8[7] = __float2bfloat16(b1.w * w1.w);
        } else {
#pragma unroll
            for (int ii = 0; ii < 8; ++ii) { at8[ii] = __float2bfloat16(0.f); bt8[ii] = __float2bfloat16(0.f); }
        }
        *(bf16x8*)&AT[m * KST + k] = *(bf16x8*)at8;
        *(bf16x8*)&BT[m * KST + k] = *(bf16x8*)bt8;
    }
    __syncthreads();

    int wv_ = __builtin_amdgcn_readfirstlane(t >> 6);
    int lane = t & 63;
    int q = lane >> 4, c = lane & 15;
    int m0 = wv_ * 16;

    f32x4 acc[4];
#pragma unroll
    for (int ct = 0; ct < 4; ++ct) acc[ct] = (f32x4){0.f, 0.f, 0.f, 0.f};

    for (int ks = 0; ks < 7; ++ks) {
        int kb = ks * 32 + q * 8;
        bf16x8 af = *(const bf16x8*)&AT[(m0 + c) * KST + kb];
#pragma unroll
        for (int ct = 0; ct < 4; ++ct) {
            bf16x8 bf_ = *(const bf16x8*)&BT[(ct * 16 + c) * KST + kb];
            acc[ct] = __builtin_amdgcn_mfma_f32_16x16x32_bf16(af, bf_, acc[ct], 0, 0, 0);
        }
    }

    float na[4], nb[4];
#pragma unroll
    for (int r = 0; r < 4; ++r) {
        int i = m0 + q * 4 + r;
        na[r] = wn[(((0 * 2 + dir) * BB + b) * SS + i) * LL + l];
    }
#pragma unroll
    for (int ct = 0; ct < 4; ++ct) {
        int j = ct * 16 + c;
        nb[ct] = wn[(((1 * 2 + dir) * BB + b) * SS + j) * LL + l];
    }

    float rowm[4] = {-INFINITY, -INFINITY, -INFINITY, -INFINITY};
    float colm[4] = {-INFINITY, -INFINITY, -INFINITY, -INFINITY};
#pragma unroll
    for (int ct = 0; ct < 4; ++ct) {
#pragma unroll
        for (int r = 0; r < 4; ++r) {
            float cv = acc[ct][r] / fmaxf(na[r] * nb[ct], EPS);
            rowm[r] = fmaxf(rowm[r], cv);
            colm[ct] = fmaxf(colm[ct], cv);
        }
    }

    // row-max across the 16 lanes (cols) of this q-group
#pragma unroll
    for (int r = 0; r < 4; ++r) {
        float v = rowm[r];
        v = fmaxf(v, __shfl_xor(v, 1, 64));
        v = fmaxf(v, __shfl_xor(v, 2, 64));
        v = fmaxf(v, __shfl_xor(v, 4, 64));
        v = fmaxf(v, __shfl_xor(v, 8, 64));
        rowm[r] = v;
    }
    if (c == 0) {
#pragma unroll
        for (int r = 0; r < 4; ++r) {
            int i = m0 + q * 4 + r;
            out[(b * SS + i) * 160 + dir * 80 + 20 + l] = rowm[r];   // mv_p chunk
        }
    }

    // col-max across q groups, then across 4 waves via LDS
#pragma unroll
    for (int ct = 0; ct < 4; ++ct) {
        float v = colm[ct];
        v = fmaxf(v, __shfl_xor(v, 16, 64));
        v = fmaxf(v, __shfl_xor(v, 32, 64));
        colm[ct] = v;
    }
    if (q == 0) {
#pragma unroll
        for (int ct = 0; ct < 4; ++ct) cmL[wv_ * 64 + ct * 16 + c] = colm[ct];
    }
    __syncthreads();
    if (t < 64) {
        float m = fmaxf(fmaxf(cmL[t], cmL[64 + t]), fmaxf(cmL[128 + t], cmL[192 + t]));
        out[BB * SS * 160 + (b * SS + t) * 160 + dir * 80 + 20 + l] = m;  // mv_h chunk
    }
}

extern "C" void kernel_launch(void* const* d_in, const int* in_sizes, int n_in,
                              void* d_out, int out_size, void* d_ws, size_t ws_size,
                              hipStream_t stream) {
    const float* conp = (const float*)d_in[0];
    const float* conh = (const float*)d_in[1];
    const float* w1 = (const float*)d_in[2];
    const float* w2 = (const float*)d_in[3];
    const float* w3 = (const float*)d_in[4];
    const float* w4 = (const float*)d_in[5];
    const float* w5 = (const float*)d_in[6];
    const float* w6 = (const float*)d_in[7];
    const float* w7 = (const float*)d_in[8];
    const float* w8 = (const float*)d_in[9];
    float* out = (float*)d_out;
    float* ws  = (float*)d_ws;

    float* att    = ws;                        // 262144
    float* n2arr  = att + 2 * BB * SS * SS;    // 8192
    float* wn     = n2arr + 4 * BB * SS;       // 163840
    float* w2pt   = wn + 4 * BB * SS * LL;     // 8000
    float* w2t    = w2pt + 2 * LL * HH;        // 24000
    float* meanv  = w2t + 6 * LL * HH;         // 1638400
    float* maxv   = meanv + 4 * BB * SS * HH;  // 1638400

    prep_kernel<<<32 + 4 * BB * SS / 4, 256, 0, stream>>>(conp, conh, w1, w2, w3, w4, w5, w6,
                                                          w7, w8, w2pt, w2t, n2arr);
    att_kernel<<<2 * BB * SS, 64, 0, stream>>>(conp, conh, n2arr, att);
    attvec_kernel<<<4 * BB * 8, 256, 0, stream>>>(conp, conh, att, meanv, maxv);
    match_kernel<<<4 * BB * SS, 64, 0, stream>>>(conp, conh, meanv, maxv, w2t, w2pt, out, wn);
    pairmfma_kernel<<<2 * BB * LL, 256, 0, stream>>>(conp, conh, w3, w4, wn, out);
}

// Round 11
// 189.907 us; speedup vs baseline: 1.3203x; 1.0556x over previous
//
#include <hip/hip_runtime.h>
#include <hip/hip_bf16.h>
#include <math.h>

#define EPS 1e-8f
#define BB 32
#define SS 64
#define HH 200
#define LL 20
#define KP 224    // pairmfma K padded to 7*32
#define KST 232   // pairmfma LDS row stride (bf16 elems)
#define MST 204   // match/prep LDS row stride (floats); 204%32=12 -> good bank spread

typedef short bf16x8 __attribute__((ext_vector_type(8)));
typedef float f32x4 __attribute__((ext_vector_type(4)));

// ws layout (floats):
// att 262144 | n2arr 8192 | wn 163840 | meanv 1638400 | maxv 1638400

// ---------------------------------------------------------------- prep: plain norms + wn
// blocks [0,2048): plain norms (4 waves x 2048 = all 8192 entries);
// blocks [2048,2304): pairwise weighted norms wn
__global__ void prep_kernel(const float* __restrict__ conp, const float* __restrict__ conh,
                            const float* __restrict__ w3, const float* __restrict__ w4,
                            float* __restrict__ n2arr, float* __restrict__ wn) {
    __shared__ __align__(16) float w2L[LL * MST];   // 16.3 KB
    __shared__ __align__(16) float x2L[32 * MST];   // 26.1 KB
    int t = threadIdx.x;
    if (blockIdx.x < 2048) {
        int wave = t >> 6, lane = t & 63;
        int e = blockIdx.x * 4 + wave;              // [0, 8192) -- FULL coverage (r10 bug: only 2048)
        int s = e & 63, b = (e >> 6) & 31, sd = e >> 11;
        int dir = sd & 1, side = sd >> 1;
        const float* v = (side ? conh : conp) + (b * SS + s) * (2 * HH) + dir * HH;
        float val = 0.f;
        if (lane < 50) {
            float4 f = ((const float4*)v)[lane];
            val = f.x * f.x + f.y * f.y + f.z * f.z + f.w * f.w;
        }
#pragma unroll
        for (int off = 32; off >= 1; off >>= 1) val += __shfl_xor(val, off, 64);
        if (lane == 0) n2arr[e] = sqrtf(val);
    } else {
        // wn: block = (sdb, s-half of 32)
        int wnb = blockIdx.x - 2048;
        int sh = wnb & 1, sdb = wnb >> 1;
        int b = sdb & 31, sd = sdb >> 5;
        int dir = sd & 1, side = sd >> 1;
        const float* wsrc = dir ? w4 : w3;
        for (int e = t; e < LL * 25; e += 256) {
            int l = e / 25, c = e % 25, h0 = c * 8;
            float4 u0 = *(const float4*)(wsrc + l * HH + h0);
            float4 u1 = *(const float4*)(wsrc + l * HH + h0 + 4);
            *(float4*)&w2L[l * MST + h0] = make_float4(u0.x * u0.x, u0.y * u0.y, u0.z * u0.z, u0.w * u0.w);
            *(float4*)&w2L[l * MST + h0 + 4] = make_float4(u1.x * u1.x, u1.y * u1.y, u1.z * u1.z, u1.w * u1.w);
        }
        const float* xbase = side ? conh : conp;
        for (int e = t; e < 32 * 25; e += 256) {
            int s_ = e / 25, c = e % 25, h0 = c * 8;
            const float* xp = xbase + (b * SS + sh * 32 + s_) * (2 * HH) + dir * HH + h0;
            float4 u0 = *(const float4*)xp;
            float4 u1 = *(const float4*)(xp + 4);
            *(float4*)&x2L[s_ * MST + h0] = make_float4(u0.x * u0.x, u0.y * u0.y, u0.z * u0.z, u0.w * u0.w);
            *(float4*)&x2L[s_ * MST + h0 + 4] = make_float4(u1.x * u1.x, u1.y * u1.y, u1.z * u1.z, u1.w * u1.w);
        }
        __syncthreads();
        for (int o = t; o < 32 * LL; o += 256) {
            int s_ = o / LL, l = o % LL;
            const float4* xp = (const float4*)&x2L[s_ * MST];
            const float4* wp = (const float4*)&w2L[l * MST];
            float a0 = 0.f, a1 = 0.f, a2 = 0.f, a3 = 0.f;
            for (int h4 = 0; h4 < 50; ++h4) {
                float4 x = xp[h4]; float4 w = wp[h4];
                a0 = fmaf(x.x, w.x, a0); a1 = fmaf(x.y, w.y, a1);
                a2 = fmaf(x.z, w.z, a2); a3 = fmaf(x.w, w.w, a3);
            }
            wn[((sd * BB + b) * SS + sh * 32 + s_) * LL + l] = sqrtf(a0 + a1 + a2 + a3);
        }
    }
}

// ---------------------------------------------------------------- attention matrix
__global__ void att_kernel(const float* __restrict__ conp, const float* __restrict__ conh,
                           const float* __restrict__ n2arr, float* __restrict__ att) {
    int blk = blockIdx.x;
    int p = blk & 63, b = (blk >> 6) & 31, dir = blk >> 11;
    int q = threadIdx.x;
    __shared__ float4 pvL[50];
    const float* pv = conp + (b * SS + p) * (2 * HH) + dir * HH;
    if (q < 50) pvL[q] = ((const float4*)pv)[q];
    __syncthreads();
    const float4* hv = (const float4*)(conh + (b * SS + q) * (2 * HH) + dir * HH);
    float dot = 0.f;
    for (int j = 0; j < 50; ++j) {
        float4 a = pvL[j]; float4 c = hv[j];
        dot = fmaf(a.x, c.x, dot); dot = fmaf(a.y, c.y, dot);
        dot = fmaf(a.z, c.z, dot); dot = fmaf(a.w, c.w, dot);
    }
    float n1 = n2arr[((0 * 2 + dir) * BB + b) * SS + p];
    float n2 = n2arr[((1 * 2 + dir) * BB + b) * SS + q];
    att[blk * SS + q] = dot / fmaxf(n1 * n2, EPS);
}

// ---------------------------------------------------------------- att-mean & att-max vectors
__global__ void attvec_kernel(const float* __restrict__ conp, const float* __restrict__ conh,
                              const float* __restrict__ att,
                              float* __restrict__ meanv, float* __restrict__ maxv) {
    int blk = blockIdx.x;
    int ht = blk & 7, b = (blk >> 3) & 31, sd = blk >> 8;
    int dir = sd & 1, side = sd >> 1;
    int t = threadIdx.x;
    __shared__ float attL[SS * 65];
    __shared__ float oppL[SS * 26];
    const float* abase = att + (dir * BB + b) * SS * SS;
    for (int e = t; e < SS * SS; e += 256) {
        int r = e >> 6, c = e & 63;
        float v = abase[e];
        if (side == 0) attL[r * 65 + c] = v;
        else           attL[c * 65 + r] = v;
    }
    const float* opp = (side == 0 ? conh : conp);
    for (int e = t; e < SS * 25; e += 256) {
        int k = e / 25, j = e - k * 25;
        oppL[k * 26 + j] = opp[(b * SS + k) * (2 * HH) + dir * HH + ht * 25 + j];
    }
    __syncthreads();
    int s = t >> 2, c3 = t & 3;
    int j0 = c3 * 7;
    float ms[7], mx[7];
#pragma unroll
    for (int i = 0; i < 7; ++i) { ms[i] = 0.f; mx[i] = -INFINITY; }
    float dn = 0.f;
    for (int k = 0; k < SS; ++k) {
        float a = attL[s * 65 + k];
        dn += a;
        int base = k * 26 + j0;
#pragma unroll
        for (int i = 0; i < 7; ++i) {
            if (j0 + i < 25) {
                float tt = a * oppL[base + i];
                ms[i] += tt;
                mx[i] = fmaxf(mx[i], tt);
            }
        }
    }
    float dd = fmaxf(dn, EPS);
    int obase = (((side * 2 + dir) * BB + b) * SS + s) * HH + ht * 25 + j0;
#pragma unroll
    for (int i = 0; i < 7; ++i) {
        if (j0 + i < 25) {
            meanv[obase + i] = ms[i] / dd;
            maxv[obase + i]  = mx[i];
        }
    }
}

// ---------------------------------------------------------------- mp_match v4 (full fp32)
// blk = ((sd*32+b)*3 + m)*4 + sq ; 320 threads; one (s,l) pair per thread.
// LDS: w^2 for this m (16.3 KB) + x^2/xy/y^2 for 16 s (13.1 KB each) = 55.5 KB.
__global__ __launch_bounds__(320) void match_kernel(
        const float* __restrict__ conp, const float* __restrict__ conh,
        const float* __restrict__ meanv, const float* __restrict__ maxv,
        const float* __restrict__ w1, const float* __restrict__ w2,
        const float* __restrict__ w5, const float* __restrict__ w6,
        const float* __restrict__ w7, const float* __restrict__ w8,
        float* __restrict__ out) {
    int blk = blockIdx.x;
    int sq = blk & 3;
    int rest = blk >> 2;
    int m = rest % 3;
    int sdb = rest / 3;
    int b = sdb & 31, sd = sdb >> 5;
    int dir = sd & 1, side = sd >> 1;
    int t = threadIdx.x;
    __shared__ __align__(16) float wL[LL * MST];    // 16.3 KB
    __shared__ __align__(16) float x2L[16 * MST];   // 13.1 KB
    __shared__ __align__(16) float xyL[16 * MST];   // 13.1 KB
    __shared__ __align__(16) float y2L[16 * MST];   // 13.1 KB

    const float* wsrc = (m == 0) ? (dir ? w2 : w1)
                      : (m == 1) ? (dir ? w6 : w5)
                                 : (dir ? w8 : w7);
    // stage w^2 (fp32)
    for (int e = t; e < LL * 25; e += 320) {
        int l = e / 25, c = e % 25, h0 = c * 8;
        float4 u0 = *(const float4*)(wsrc + l * HH + h0);
        float4 u1 = *(const float4*)(wsrc + l * HH + h0 + 4);
        *(float4*)&wL[l * MST + h0]     = make_float4(u0.x * u0.x, u0.y * u0.y, u0.z * u0.z, u0.w * u0.w);
        *(float4*)&wL[l * MST + h0 + 4] = make_float4(u1.x * u1.x, u1.y * u1.y, u1.z * u1.z, u1.w * u1.w);
    }

    // stage x^2, x*y, y^2 (fp32) for 16 s
    const float* xbase = side ? conh : conp;
    const float* opp   = side ? conp : conh;
    int fidx = dir ? 0 : (SS - 1);
    const float* fvr = opp + (b * SS + fidx) * (2 * HH) + dir * HH;
    for (int e = t; e < 16 * 25; e += 320) {
        int sl = e / 25, c = e % 25, h0 = c * 8;
        int s = sq * 16 + sl;
        const float* xp = xbase + (b * SS + s) * (2 * HH) + dir * HH + h0;
        const float* yp = (m == 0) ? (fvr + h0)
                        : ((m == 1 ? meanv : maxv) + ((sd * BB + b) * SS + s) * HH + h0);
        float xv[8], yv[8];
        *(float4*)&xv[0] = *(const float4*)xp; *(float4*)&xv[4] = *(const float4*)(xp + 4);
        *(float4*)&yv[0] = *(const float4*)yp; *(float4*)&yv[4] = *(const float4*)(yp + 4);
        float x2[8], xy[8], y2[8];
#pragma unroll
        for (int k = 0; k < 8; ++k) {
            x2[k] = xv[k] * xv[k];
            xy[k] = xv[k] * yv[k];
            y2[k] = yv[k] * yv[k];
        }
        *(float4*)&x2L[sl * MST + h0]     = *(float4*)&x2[0];
        *(float4*)&x2L[sl * MST + h0 + 4] = *(float4*)&x2[4];
        *(float4*)&xyL[sl * MST + h0]     = *(float4*)&xy[0];
        *(float4*)&xyL[sl * MST + h0 + 4] = *(float4*)&xy[4];
        *(float4*)&y2L[sl * MST + h0]     = *(float4*)&y2[0];
        *(float4*)&y2L[sl * MST + h0 + 4] = *(float4*)&y2[4];
    }
    __syncthreads();

    // one (sl, l) pair per thread
    int sl = t / 20, l = t - sl * 20;
    const float4* wp = (const float4*)&wL[l * MST];
    const float4* xp = (const float4*)&x2L[sl * MST];
    const float4* pp = (const float4*)&xyL[sl * MST];
    const float4* zp = (const float4*)&y2L[sl * MST];
    float d0 = 0, d1 = 0, d2 = 0, d3 = 0;
    float a0 = 0, a1 = 0, a2 = 0, a3 = 0;
    float b0 = 0, b1 = 0, b2 = 0, b3 = 0;
    for (int h4 = 0; h4 < 50; ++h4) {
        float4 w = wp[h4];
        float4 x = xp[h4];
        float4 y = pp[h4];
        float4 z = zp[h4];
        d0 = fmaf(y.x, w.x, d0); d1 = fmaf(y.y, w.y, d1);
        d2 = fmaf(y.z, w.z, d2); d3 = fmaf(y.w, w.w, d3);
        a0 = fmaf(x.x, w.x, a0); a1 = fmaf(x.y, w.y, a1);
        a2 = fmaf(x.z, w.z, a2); a3 = fmaf(x.w, w.w, a3);
        b0 = fmaf(z.x, w.x, b0); b1 = fmaf(z.y, w.y, b1);
        b2 = fmaf(z.z, w.z, b2); b3 = fmaf(z.w, w.w, b3);
    }
    float d = (d0 + d1) + (d2 + d3);
    float a = (a0 + a1) + (a2 + a3);
    float bb = (b0 + b1) + (b2 + b3);
    float cosv = d / fmaxf(sqrtf(a * bb), EPS);
    int chunk = (m == 0) ? 0 : (m == 1) ? 40 : 60;
    int s = sq * 16 + sl;
    out[side * (BB * SS * 160) + (b * SS + s) * 160 + dir * 80 + chunk + l] = cosv;
}

// ---------------------------------------------------------------- pairwise via bf16 MFMA
__global__ __launch_bounds__(256) void pairmfma_kernel(
        const float* __restrict__ conp, const float* __restrict__ conh,
        const float* __restrict__ w3, const float* __restrict__ w4,
        const float* __restrict__ wn, float* __restrict__ out) {
    int blk = blockIdx.x;
    int l = blk % LL; int db = blk / LL; int b = db & 31; int dir = db >> 5;
    int t = threadIdx.x;
    __shared__ __hip_bfloat16 AT[64 * KST];
    __shared__ __hip_bfloat16 BT[64 * KST];
    __shared__ float cmL[4 * 64];

    const float* wrow = (dir ? w4 : w3) + l * HH;
    const float* Ag = conp + dir * HH;
    const float* Bg = conh + dir * HH;

    for (int e = t; e < 64 * 28; e += 256) {
        int m = e / 28, ck = e - m * 28;
        int k = ck * 8;
        __align__(16) __hip_bfloat16 at8[8];
        __align__(16) __hip_bfloat16 bt8[8];
        if (k < HH) {
            const float* ap = Ag + (b * SS + m) * (2 * HH) + k;
            const float* bp = Bg + (b * SS + m) * (2 * HH) + k;
            const float* wp = wrow + k;
            float4 a0 = *(const float4*)ap, a1 = *(const float4*)(ap + 4);
            float4 b0 = *(const float4*)bp, b1 = *(const float4*)(bp + 4);
            float4 w0 = *(const float4*)wp, w1 = *(const float4*)(wp + 4);
            at8[0] = __float2bfloat16(a0.x * w0.x); at8[1] = __float2bfloat16(a0.y * w0.y);
            at8[2] = __float2bfloat16(a0.z * w0.z); at8[3] = __float2bfloat16(a0.w * w0.w);
            at8[4] = __float2bfloat16(a1.x * w1.x); at8[5] = __float2bfloat16(a1.y * w1.y);
            at8[6] = __float2bfloat16(a1.z * w1.z); at8[7] = __float2bfloat16(a1.w * w1.w);
            bt8[0] = __float2bfloat16(b0.x * w0.x); bt8[1] = __float2bfloat16(b0.y * w0.y);
            bt8[2] = __float2bfloat16(b0.z * w0.z); bt8[3] = __float2bfloat16(b0.w * w0.w);
            bt8[4] = __float2bfloat16(b1.x * w1.x); bt8[5] = __float2bfloat16(b1.y * w1.y);
            bt8[6] = __float2bfloat16(b1.z * w1.z); bt8[7] = __float2bfloat16(b1.w * w1.w);
        } else {
#pragma unroll
            for (int ii = 0; ii < 8; ++ii) { at8[ii] = __float2bfloat16(0.f); bt8[ii] = __float2bfloat16(0.f); }
        }
        *(bf16x8*)&AT[m * KST + k] = *(bf16x8*)at8;
        *(bf16x8*)&BT[m * KST + k] = *(bf16x8*)bt8;
    }
    __syncthreads();

    int wv_ = __builtin_amdgcn_readfirstlane(t >> 6);
    int lane = t & 63;
    int q = lane >> 4, c = lane & 15;
    int m0 = wv_ * 16;

    f32x4 acc[4];
#pragma unroll
    for (int ct = 0; ct < 4; ++ct) acc[ct] = (f32x4){0.f, 0.f, 0.f, 0.f};

    for (int ks = 0; ks < 7; ++ks) {
        int kb = ks * 32 + q * 8;
        bf16x8 af = *(const bf16x8*)&AT[(m0 + c) * KST + kb];
#pragma unroll
        for (int ct = 0; ct < 4; ++ct) {
            bf16x8 bf_ = *(const bf16x8*)&BT[(ct * 16 + c) * KST + kb];
            acc[ct] = __builtin_amdgcn_mfma_f32_16x16x32_bf16(af, bf_, acc[ct], 0, 0, 0);
        }
    }

    float na[4], nb[4];
#pragma unroll
    for (int r = 0; r < 4; ++r) {
        int i = m0 + q * 4 + r;
        na[r] = wn[(((0 * 2 + dir) * BB + b) * SS + i) * LL + l];
    }
#pragma unroll
    for (int ct = 0; ct < 4; ++ct) {
        int j = ct * 16 + c;
        nb[ct] = wn[(((1 * 2 + dir) * BB + b) * SS + j) * LL + l];
    }

    float rowm[4] = {-INFINITY, -INFINITY, -INFINITY, -INFINITY};
    float colm[4] = {-INFINITY, -INFINITY, -INFINITY, -INFINITY};
#pragma unroll
    for (int ct = 0; ct < 4; ++ct) {
#pragma unroll
        for (int r = 0; r < 4; ++r) {
            float cv = acc[ct][r] / fmaxf(na[r] * nb[ct], EPS);
            rowm[r] = fmaxf(rowm[r], cv);
            colm[ct] = fmaxf(colm[ct], cv);
        }
    }

#pragma unroll
    for (int r = 0; r < 4; ++r) {
        float v = rowm[r];
        v = fmaxf(v, __shfl_xor(v, 1, 64));
        v = fmaxf(v, __shfl_xor(v, 2, 64));
        v = fmaxf(v, __shfl_xor(v, 4, 64));
        v = fmaxf(v, __shfl_xor(v, 8, 64));
        rowm[r] = v;
    }
    if (c == 0) {
#pragma unroll
        for (int r = 0; r < 4; ++r) {
            int i = m0 + q * 4 + r;
            out[(b * SS + i) * 160 + dir * 80 + 20 + l] = rowm[r];
        }
    }

#pragma unroll
    for (int ct = 0; ct < 4; ++ct) {
        float v = colm[ct];
        v = fmaxf(v, __shfl_xor(v, 16, 64));
        v = fmaxf(v, __shfl_xor(v, 32, 64));
        colm[ct] = v;
    }
    if (q == 0) {
#pragma unroll
        for (int ct = 0; ct < 4; ++ct) cmL[wv_ * 64 + ct * 16 + c] = colm[ct];
    }
    __syncthreads();
    if (t < 64) {
        float m = fmaxf(fmaxf(cmL[t], cmL[64 + t]), fmaxf(cmL[128 + t], cmL[192 + t]));
        out[BB * SS * 160 + (b * SS + t) * 160 + dir * 80 + 20 + l] = m;
    }
}

extern "C" void kernel_launch(void* const* d_in, const int* in_sizes, int n_in,
                              void* d_out, int out_size, void* d_ws, size_t ws_size,
                              hipStream_t stream) {
    const float* conp = (const float*)d_in[0];
    const float* conh = (const float*)d_in[1];
    const float* w1 = (const float*)d_in[2];
    const float* w2 = (const float*)d_in[3];
    const float* w3 = (const float*)d_in[4];
    const float* w4 = (const float*)d_in[5];
    const float* w5 = (const float*)d_in[6];
    const float* w6 = (const float*)d_in[7];
    const float* w7 = (const float*)d_in[8];
    const float* w8 = (const float*)d_in[9];
    float* out = (float*)d_out;
    float* ws  = (float*)d_ws;

    float* att    = ws;                        // 262144
    float* n2arr  = att + 2 * BB * SS * SS;    // 8192
    float* wn     = n2arr + 4 * BB * SS;       // 163840
    float* meanv  = wn + 4 * BB * SS * LL;     // 1638400
    float* maxv   = meanv + 4 * BB * SS * HH;  // 1638400

    prep_kernel<<<2048 + 256, 256, 0, stream>>>(conp, conh, w3, w4, n2arr, wn);
    att_kernel<<<2 * BB * SS, 64, 0, stream>>>(conp, conh, n2arr, att);
    attvec_kernel<<<4 * BB * 8, 256, 0, stream>>>(conp, conh, att, meanv, maxv);
    match_kernel<<<4 * BB * 3 * 4, 320, 0, stream>>>(conp, conh, meanv, maxv,
                                                     w1, w2, w5, w6, w7, w8, out);
    pairmfma_kernel<<<2 * BB * LL, 256, 0, stream>>>(conp, conh, w3, w4, wn, out);
}

// Round 12
// 163.049 us; speedup vs baseline: 1.5378x; 1.1647x over previous
//
#include <hip/hip_runtime.h>
#include <hip/hip_bf16.h>
#include <math.h>

#define EPS 1e-8f
#define BB 32
#define SS 64
#define HH 200
#define LL 20
#define KP 224    // K padded to 7*32
#define KST 232   // LDS row stride (bf16 elems), 16B-aligned, good bank spread
#define MST 204   // prep LDS row stride (floats)

typedef short bf16x8 __attribute__((ext_vector_type(8)));
typedef float f32x4 __attribute__((ext_vector_type(4)));

// ws layout (floats): att 262144 | wn 163840 | meanv 1638400 | maxv 1638400

// ---------------------------------------------------------------- prep: pairwise weighted norms wn
// block = (sdb, s-half of 32); 256 blocks
__global__ void prep_kernel(const float* __restrict__ conp, const float* __restrict__ conh,
                            const float* __restrict__ w3, const float* __restrict__ w4,
                            float* __restrict__ wn) {
    __shared__ __align__(16) float w2L[LL * MST];
    __shared__ __align__(16) float x2L[32 * MST];
    int t = threadIdx.x;
    int wnb = blockIdx.x;
    int sh = wnb & 1, sdb = wnb >> 1;
    int b = sdb & 31, sd = sdb >> 5;
    int dir = sd & 1, side = sd >> 1;
    const float* wsrc = dir ? w4 : w3;
    for (int e = t; e < LL * 25; e += 256) {
        int l = e / 25, c = e % 25, h0 = c * 8;
        float4 u0 = *(const float4*)(wsrc + l * HH + h0);
        float4 u1 = *(const float4*)(wsrc + l * HH + h0 + 4);
        *(float4*)&w2L[l * MST + h0]     = make_float4(u0.x * u0.x, u0.y * u0.y, u0.z * u0.z, u0.w * u0.w);
        *(float4*)&w2L[l * MST + h0 + 4] = make_float4(u1.x * u1.x, u1.y * u1.y, u1.z * u1.z, u1.w * u1.w);
    }
    const float* xbase = side ? conh : conp;
    for (int e = t; e < 32 * 25; e += 256) {
        int s_ = e / 25, c = e % 25, h0 = c * 8;
        const float* xp = xbase + (b * SS + sh * 32 + s_) * (2 * HH) + dir * HH + h0;
        float4 u0 = *(const float4*)xp;
        float4 u1 = *(const float4*)(xp + 4);
        *(float4*)&x2L[s_ * MST + h0]     = make_float4(u0.x * u0.x, u0.y * u0.y, u0.z * u0.z, u0.w * u0.w);
        *(float4*)&x2L[s_ * MST + h0 + 4] = make_float4(u1.x * u1.x, u1.y * u1.y, u1.z * u1.z, u1.w * u1.w);
    }
    __syncthreads();
    for (int o = t; o < 32 * LL; o += 256) {
        int s_ = o / LL, l = o % LL;
        const float4* xp = (const float4*)&x2L[s_ * MST];
        const float4* wp = (const float4*)&w2L[l * MST];
        float a0 = 0.f, a1 = 0.f, a2 = 0.f, a3 = 0.f;
        for (int h4 = 0; h4 < 50; ++h4) {
            float4 x = xp[h4]; float4 w = wp[h4];
            a0 = fmaf(x.x, w.x, a0); a1 = fmaf(x.y, w.y, a1);
            a2 = fmaf(x.z, w.z, a2); a3 = fmaf(x.w, w.w, a3);
        }
        wn[((sd * BB + b) * SS + sh * 32 + s_) * LL + l] = sqrtf(a0 + a1 + a2 + a3);
    }
}

// ---------------------------------------------------------------- attention matrix (norms inline)
__global__ void att_kernel(const float* __restrict__ conp, const float* __restrict__ conh,
                           float* __restrict__ att) {
    int blk = blockIdx.x;
    int p = blk & 63, b = (blk >> 6) & 31, dir = blk >> 11;
    int q = threadIdx.x;
    __shared__ float4 pvL[50];
    const float* pv = conp + (b * SS + p) * (2 * HH) + dir * HH;
    if (q < 50) pvL[q] = ((const float4*)pv)[q];
    __syncthreads();
    const float4* hv = (const float4*)(conh + (b * SS + q) * (2 * HH) + dir * HH);
    float dot = 0.f, pp = 0.f, qq = 0.f;
    for (int j = 0; j < 50; ++j) {
        float4 a = pvL[j]; float4 c = hv[j];
        dot = fmaf(a.x, c.x, dot); dot = fmaf(a.y, c.y, dot);
        dot = fmaf(a.z, c.z, dot); dot = fmaf(a.w, c.w, dot);
        pp  = fmaf(a.x, a.x, pp);  pp  = fmaf(a.y, a.y, pp);
        pp  = fmaf(a.z, a.z, pp);  pp  = fmaf(a.w, a.w, pp);
        qq  = fmaf(c.x, c.x, qq);  qq  = fmaf(c.y, c.y, qq);
        qq  = fmaf(c.z, c.z, qq);  qq  = fmaf(c.w, c.w, qq);
    }
    att[blk * SS + q] = dot / fmaxf(sqrtf(pp) * sqrtf(qq), EPS);
}

// ---------------------------------------------------------------- att-mean & att-max vectors
__global__ void attvec_kernel(const float* __restrict__ conp, const float* __restrict__ conh,
                              const float* __restrict__ att,
                              float* __restrict__ meanv, float* __restrict__ maxv) {
    int blk = blockIdx.x;
    int ht = blk & 7, b = (blk >> 3) & 31, sd = blk >> 8;
    int dir = sd & 1, side = sd >> 1;
    int t = threadIdx.x;
    __shared__ float attL[SS * 65];
    __shared__ float oppL[SS * 26];
    const float* abase = att + (dir * BB + b) * SS * SS;
    for (int e = t; e < SS * SS; e += 256) {
        int r = e >> 6, c = e & 63;
        float v = abase[e];
        if (side == 0) attL[r * 65 + c] = v;
        else           attL[c * 65 + r] = v;
    }
    const float* opp = (side == 0 ? conh : conp);
    for (int e = t; e < SS * 25; e += 256) {
        int k = e / 25, j = e - k * 25;
        oppL[k * 26 + j] = opp[(b * SS + k) * (2 * HH) + dir * HH + ht * 25 + j];
    }
    __syncthreads();
    int s = t >> 2, c3 = t & 3;
    int j0 = c3 * 7;
    float ms[7], mx[7];
#pragma unroll
    for (int i = 0; i < 7; ++i) { ms[i] = 0.f; mx[i] = -INFINITY; }
    float dn = 0.f;
    for (int k = 0; k < SS; ++k) {
        float a = attL[s * 65 + k];
        dn += a;
        int base = k * 26 + j0;
#pragma unroll
        for (int i = 0; i < 7; ++i) {
            if (j0 + i < 25) {
                float tt = a * oppL[base + i];
                ms[i] += tt;
                mx[i] = fmaxf(mx[i], tt);
            }
        }
    }
    float dd = fmaxf(dn, EPS);
    int obase = (((side * 2 + dir) * BB + b) * SS + s) * HH + ht * 25 + j0;
#pragma unroll
    for (int i = 0; i < 7; ++i) {
        if (j0 + i < 25) {
            meanv[obase + i] = ms[i] / dd;
            maxv[obase + i]  = mx[i];
        }
    }
}

// ---------------------------------------------------------------- mp_match v5: bf16 MFMA
// blk = ((sd*32+b)*3 + m)*2 + sh ; 256 thr / 4 waves.
// A' rows [type*32 + sl]: type0=x^2, type1=x*y, type2=y^2 (32 s, K=224 bf16); B' rows l: w^2.
// wave w: slhalf = w>>1, ntile = w&1; 3 MFMA accs (one per type) -> cosine in epilogue.
__global__ __launch_bounds__(256) void match_kernel(
        const float* __restrict__ conp, const float* __restrict__ conh,
        const float* __restrict__ meanv, const float* __restrict__ maxv,
        const float* __restrict__ w1, const float* __restrict__ w2,
        const float* __restrict__ w5, const float* __restrict__ w6,
        const float* __restrict__ w7, const float* __restrict__ w8,
        float* __restrict__ out) {
    int blk = blockIdx.x;
    int sh = blk & 1;
    int r_ = blk >> 1;
    int m = r_ % 3;
    int sdb = r_ / 3;
    int b = sdb & 31, sd = sdb >> 5;
    int dir = sd & 1, side = sd >> 1;
    int t = threadIdx.x;
    __shared__ __hip_bfloat16 AT[96 * KST];   // 44.5 KB
    __shared__ __hip_bfloat16 BT[32 * KST];   // 14.8 KB

    const float* wsrc = (m == 0) ? (dir ? w2 : w1)
                      : (m == 1) ? (dir ? w6 : w5)
                                 : (dir ? w8 : w7);
    const float* xbase = side ? conh : conp;
    const float* opp   = side ? conp : conh;
    int fidx = dir ? 0 : (SS - 1);
    const float* fvr = opp + (b * SS + fidx) * (2 * HH) + dir * HH;

    // stage A': 32 sl x 28 chunks, 3 type-rows each
    for (int e = t; e < 32 * 28; e += 256) {
        int sl = e / 28, ck = e % 28;
        int k = ck * 8;
        int s = sh * 32 + sl;
        __align__(16) __hip_bfloat16 r0[8], r1[8], r2[8];
        if (k < HH) {
            const float* xp = xbase + (b * SS + s) * (2 * HH) + dir * HH + k;
            const float* yp = (m == 0) ? (fvr + k)
                            : ((m == 1 ? meanv : maxv) + ((sd * BB + b) * SS + s) * HH + k);
            float xv[8], yv[8];
            *(float4*)&xv[0] = *(const float4*)xp; *(float4*)&xv[4] = *(const float4*)(xp + 4);
            *(float4*)&yv[0] = *(const float4*)yp; *(float4*)&yv[4] = *(const float4*)(yp + 4);
#pragma unroll
            for (int i = 0; i < 8; ++i) {
                r0[i] = __float2bfloat16(xv[i] * xv[i]);
                r1[i] = __float2bfloat16(xv[i] * yv[i]);
                r2[i] = __float2bfloat16(yv[i] * yv[i]);
            }
        } else {
#pragma unroll
            for (int i = 0; i < 8; ++i) {
                r0[i] = __float2bfloat16(0.f); r1[i] = __float2bfloat16(0.f); r2[i] = __float2bfloat16(0.f);
            }
        }
        *(bf16x8*)&AT[(0 * 32 + sl) * KST + k] = *(bf16x8*)r0;
        *(bf16x8*)&AT[(1 * 32 + sl) * KST + k] = *(bf16x8*)r1;
        *(bf16x8*)&AT[(2 * 32 + sl) * KST + k] = *(bf16x8*)r2;
    }
    // stage B': 32 l-rows x 28 chunks (l>=20 or k>=200 -> zero)
    for (int e = t; e < 32 * 28; e += 256) {
        int l = e / 28, ck = e % 28;
        int k = ck * 8;
        __align__(16) __hip_bfloat16 wr[8];
        if (l < LL && k < HH) {
            const float* wp = wsrc + l * HH + k;
            float wv[8];
            *(float4*)&wv[0] = *(const float4*)wp; *(float4*)&wv[4] = *(const float4*)(wp + 4);
#pragma unroll
            for (int i = 0; i < 8; ++i) wr[i] = __float2bfloat16(wv[i] * wv[i]);
        } else {
#pragma unroll
            for (int i = 0; i < 8; ++i) wr[i] = __float2bfloat16(0.f);
        }
        *(bf16x8*)&BT[l * KST + k] = *(bf16x8*)wr;
    }
    __syncthreads();

    int wv_ = __builtin_amdgcn_readfirstlane(t >> 6);
    int lane = t & 63;
    int q = lane >> 4, c = lane & 15;
    int slh = wv_ >> 1, ntile = wv_ & 1;

    f32x4 accA = (f32x4){0.f, 0.f, 0.f, 0.f};   // x^2 . w^2
    f32x4 accD = (f32x4){0.f, 0.f, 0.f, 0.f};   // xy  . w^2
    f32x4 accB = (f32x4){0.f, 0.f, 0.f, 0.f};   // y^2 . w^2
    for (int ks = 0; ks < 7; ++ks) {
        int kb = ks * 32 + q * 8;
        bf16x8 bf = *(const bf16x8*)&BT[(ntile * 16 + c) * KST + kb];
        bf16x8 a0 = *(const bf16x8*)&AT[(0 * 32 + slh * 16 + c) * KST + kb];
        bf16x8 a1 = *(const bf16x8*)&AT[(1 * 32 + slh * 16 + c) * KST + kb];
        bf16x8 a2 = *(const bf16x8*)&AT[(2 * 32 + slh * 16 + c) * KST + kb];
        accA = __builtin_amdgcn_mfma_f32_16x16x32_bf16(a0, bf, accA, 0, 0, 0);
        accD = __builtin_amdgcn_mfma_f32_16x16x32_bf16(a1, bf, accD, 0, 0, 0);
        accB = __builtin_amdgcn_mfma_f32_16x16x32_bf16(a2, bf, accB, 0, 0, 0);
    }

    int l = ntile * 16 + c;
    if (l < LL) {
        int chunk = (m == 0) ? 0 : (m == 1) ? 40 : 60;
#pragma unroll
        for (int r = 0; r < 4; ++r) {
            int s = sh * 32 + slh * 16 + q * 4 + r;
            float cosv = accD[r] / fmaxf(sqrtf(accA[r] * accB[r]), EPS);
            out[side * (BB * SS * 160) + (b * SS + s) * 160 + dir * 80 + chunk + l] = cosv;
        }
    }
}

// ---------------------------------------------------------------- pairwise via bf16 MFMA
__global__ __launch_bounds__(256) void pairmfma_kernel(
        const float* __restrict__ conp, const float* __restrict__ conh,
        const float* __restrict__ w3, const float* __restrict__ w4,
        const float* __restrict__ wn, float* __restrict__ out) {
    int blk = blockIdx.x;
    int l = blk % LL; int db = blk / LL; int b = db & 31; int dir = db >> 5;
    int t = threadIdx.x;
    __shared__ __hip_bfloat16 AT[64 * KST];
    __shared__ __hip_bfloat16 BT[64 * KST];
    __shared__ float cmL[4 * 64];

    const float* wrow = (dir ? w4 : w3) + l * HH;
    const float* Ag = conp + dir * HH;
    const float* Bg = conh + dir * HH;

    for (int e = t; e < 64 * 28; e += 256) {
        int m = e / 28, ck = e - m * 28;
        int k = ck * 8;
        __align__(16) __hip_bfloat16 at8[8];
        __align__(16) __hip_bfloat16 bt8[8];
        if (k < HH) {
            const float* ap = Ag + (b * SS + m) * (2 * HH) + k;
            const float* bp = Bg + (b * SS + m) * (2 * HH) + k;
            const float* wp = wrow + k;
            float4 a0 = *(const float4*)ap, a1 = *(const float4*)(ap + 4);
            float4 b0 = *(const float4*)bp, b1 = *(const float4*)(bp + 4);
            float4 w0 = *(const float4*)wp, w1 = *(const float4*)(wp + 4);
            at8[0] = __float2bfloat16(a0.x * w0.x); at8[1] = __float2bfloat16(a0.y * w0.y);
            at8[2] = __float2bfloat16(a0.z * w0.z); at8[3] = __float2bfloat16(a0.w * w0.w);
            at8[4] = __float2bfloat16(a1.x * w1.x); at8[5] = __float2bfloat16(a1.y * w1.y);
            at8[6] = __float2bfloat16(a1.z * w1.z); at8[7] = __float2bfloat16(a1.w * w1.w);
            bt8[0] = __float2bfloat16(b0.x * w0.x); bt8[1] = __float2bfloat16(b0.y * w0.y);
            bt8[2] = __float2bfloat16(b0.z * w0.z); bt8[3] = __float2bfloat16(b0.w * w0.w);
            bt8[4] = __float2bfloat16(b1.x * w1.x); bt8[5] = __float2bfloat16(b1.y * w1.y);
            bt8[6] = __float2bfloat16(b1.z * w1.z); bt8[7] = __float2bfloat16(b1.w * w1.w);
        } else {
#pragma unroll
            for (int ii = 0; ii < 8; ++ii) { at8[ii] = __float2bfloat16(0.f); bt8[ii] = __float2bfloat16(0.f); }
        }
        *(bf16x8*)&AT[m * KST + k] = *(bf16x8*)at8;
        *(bf16x8*)&BT[m * KST + k] = *(bf16x8*)bt8;
    }
    __syncthreads();

    int wv_ = __builtin_amdgcn_readfirstlane(t >> 6);
    int lane = t & 63;
    int q = lane >> 4, c = lane & 15;
    int m0 = wv_ * 16;

    f32x4 acc[4];
#pragma unroll
    for (int ct = 0; ct < 4; ++ct) acc[ct] = (f32x4){0.f, 0.f, 0.f, 0.f};

    for (int ks = 0; ks < 7; ++ks) {
        int kb = ks * 32 + q * 8;
        bf16x8 af = *(const bf16x8*)&AT[(m0 + c) * KST + kb];
#pragma unroll
        for (int ct = 0; ct < 4; ++ct) {
            bf16x8 bf_ = *(const bf16x8*)&BT[(ct * 16 + c) * KST + kb];
            acc[ct] = __builtin_amdgcn_mfma_f32_16x16x32_bf16(af, bf_, acc[ct], 0, 0, 0);
        }
    }

    float na[4], nb[4];
#pragma unroll
    for (int r = 0; r < 4; ++r) {
        int i = m0 + q * 4 + r;
        na[r] = wn[(((0 * 2 + dir) * BB + b) * SS + i) * LL + l];
    }
#pragma unroll
    for (int ct = 0; ct < 4; ++ct) {
        int j = ct * 16 + c;
        nb[ct] = wn[(((1 * 2 + dir) * BB + b) * SS + j) * LL + l];
    }

    float rowm[4] = {-INFINITY, -INFINITY, -INFINITY, -INFINITY};
    float colm[4] = {-INFINITY, -INFINITY, -INFINITY, -INFINITY};
#pragma unroll
    for (int ct = 0; ct < 4; ++ct) {
#pragma unroll
        for (int r = 0; r < 4; ++r) {
            float cv = acc[ct][r] / fmaxf(na[r] * nb[ct], EPS);
            rowm[r] = fmaxf(rowm[r], cv);
            colm[ct] = fmaxf(colm[ct], cv);
        }
    }

#pragma unroll
    for (int r = 0; r < 4; ++r) {
        float v = rowm[r];
        v = fmaxf(v, __shfl_xor(v, 1, 64));
        v = fmaxf(v, __shfl_xor(v, 2, 64));
        v = fmaxf(v, __shfl_xor(v, 4, 64));
        v = fmaxf(v, __shfl_xor(v, 8, 64));
        rowm[r] = v;
    }
    if (c == 0) {
#pragma unroll
        for (int r = 0; r < 4; ++r) {
            int i = m0 + q * 4 + r;
            out[(b * SS + i) * 160 + dir * 80 + 20 + l] = rowm[r];
        }
    }

#pragma unroll
    for (int ct = 0; ct < 4; ++ct) {
        float v = colm[ct];
        v = fmaxf(v, __shfl_xor(v, 16, 64));
        v = fmaxf(v, __shfl_xor(v, 32, 64));
        colm[ct] = v;
    }
    if (q == 0) {
#pragma unroll
        for (int ct = 0; ct < 4; ++ct) cmL[wv_ * 64 + ct * 16 + c] = colm[ct];
    }
    __syncthreads();
    if (t < 64) {
        float m = fmaxf(fmaxf(cmL[t], cmL[64 + t]), fmaxf(cmL[128 + t], cmL[192 + t]));
        out[BB * SS * 160 + (b * SS + t) * 160 + dir * 80 + 20 + l] = m;
    }
}

extern "C" void kernel_launch(void* const* d_in, const int* in_sizes, int n_in,
                              void* d_out, int out_size, void* d_ws, size_t ws_size,
                              hipStream_t stream) {
    const float* conp = (const float*)d_in[0];
    const float* conh = (const float*)d_in[1];
    const float* w1 = (const float*)d_in[2];
    const float* w2 = (const float*)d_in[3];
    const float* w3 = (const float*)d_in[4];
    const float* w4 = (const float*)d_in[5];
    const float* w5 = (const float*)d_in[6];
    const float* w6 = (const float*)d_in[7];
    const float* w7 = (const float*)d_in[8];
    const float* w8 = (const float*)d_in[9];
    float* out = (float*)d_out;
    float* ws  = (float*)d_ws;

    float* att    = ws;                        // 262144
    float* wn     = att + 2 * BB * SS * SS;    // 163840
    float* meanv  = wn + 4 * BB * SS * LL;     // 1638400
    float* maxv   = meanv + 4 * BB * SS * HH;  // 1638400

    att_kernel<<<2 * BB * SS, 64, 0, stream>>>(conp, conh, att);
    prep_kernel<<<256, 256, 0, stream>>>(conp, conh, w3, w4, wn);
    attvec_kernel<<<4 * BB * 8, 256, 0, stream>>>(conp, conh, att, meanv, maxv);
    match_kernel<<<4 * BB * 3 * 2, 256, 0, stream>>>(conp, conh, meanv, maxv,
                                                     w1, w2, w5, w6, w7, w8, out);
    pairmfma_kernel<<<2 * BB * LL, 256, 0, stream>>>(conp, conh, w3, w4, wn, out);
}

// Round 13
// 137.684 us; speedup vs baseline: 1.8211x; 1.1842x over previous
//
#include <hip/hip_runtime.h>
#include <hip/hip_bf16.h>
#include <math.h>

#define EPS 1e-8f
#define BB 32
#define SS 64
#define HH 200
#define LL 20
#define KP 224    // K padded to 7*32
#define KST 232   // LDS row stride (bf16 elems), 16B-aligned, good bank spread
#define MST 204   // prep LDS row stride (floats)
#define SST 68    // att S-tile LDS row stride (floats)

typedef short bf16x8 __attribute__((ext_vector_type(8)));
typedef float f32x4 __attribute__((ext_vector_type(4)));

__device__ inline float bf2f(short u) {
    union { unsigned int i; float f; } v;
    v.i = ((unsigned int)(unsigned short)u) << 16;
    return v.f;
}

// ws layout (floats): wn 163840 | meanv 1638400 | maxv 1638400

// ---------------------------------------------------------------- prep: pairwise weighted norms wn
__global__ void prep_kernel(const float* __restrict__ conp, const float* __restrict__ conh,
                            const float* __restrict__ w3, const float* __restrict__ w4,
                            float* __restrict__ wn) {
    __shared__ __align__(16) float w2L[LL * MST];
    __shared__ __align__(16) float x2L[32 * MST];
    int t = threadIdx.x;
    int wnb = blockIdx.x;
    int sh = wnb & 1, sdb = wnb >> 1;
    int b = sdb & 31, sd = sdb >> 5;
    int dir = sd & 1, side = sd >> 1;
    const float* wsrc = dir ? w4 : w3;
    for (int e = t; e < LL * 25; e += 256) {
        int l = e / 25, c = e % 25, h0 = c * 8;
        float4 u0 = *(const float4*)(wsrc + l * HH + h0);
        float4 u1 = *(const float4*)(wsrc + l * HH + h0 + 4);
        *(float4*)&w2L[l * MST + h0]     = make_float4(u0.x * u0.x, u0.y * u0.y, u0.z * u0.z, u0.w * u0.w);
        *(float4*)&w2L[l * MST + h0 + 4] = make_float4(u1.x * u1.x, u1.y * u1.y, u1.z * u1.z, u1.w * u1.w);
    }
    const float* xbase = side ? conh : conp;
    for (int e = t; e < 32 * 25; e += 256) {
        int s_ = e / 25, c = e % 25, h0 = c * 8;
        const float* xp = xbase + (b * SS + sh * 32 + s_) * (2 * HH) + dir * HH + h0;
        float4 u0 = *(const float4*)xp;
        float4 u1 = *(const float4*)(xp + 4);
        *(float4*)&x2L[s_ * MST + h0]     = make_float4(u0.x * u0.x, u0.y * u0.y, u0.z * u0.z, u0.w * u0.w);
        *(float4*)&x2L[s_ * MST + h0 + 4] = make_float4(u1.x * u1.x, u1.y * u1.y, u1.z * u1.z, u1.w * u1.w);
    }
    __syncthreads();
    for (int o = t; o < 32 * LL; o += 256) {
        int s_ = o / LL, l = o % LL;
        const float4* xp = (const float4*)&x2L[s_ * MST];
        const float4* wp = (const float4*)&w2L[l * MST];
        float a0 = 0.f, a1 = 0.f, a2 = 0.f, a3 = 0.f;
        for (int h4 = 0; h4 < 50; ++h4) {
            float4 x = xp[h4]; float4 w = wp[h4];
            a0 = fmaf(x.x, w.x, a0); a1 = fmaf(x.y, w.y, a1);
            a2 = fmaf(x.z, w.z, a2); a3 = fmaf(x.w, w.w, a3);
        }
        wn[((sd * BB + b) * SS + sh * 32 + s_) * LL + l] = sqrtf(a0 + a1 + a2 + a3);
    }
}

// ---------------------------------------------------------------- fused att + attvec
// blk = (sd*BB + b)*2 + sh ; 256 thr / 4 waves.
// Computes S[s,k] = cos(self_{sh*32+s}, opp_k) via bf16 MFMA (side=1 gives att^T rows
// without any transpose), then meanv/maxv for the 32 self rows from S and the staged opp tile.
__global__ __launch_bounds__(256) void attfused_kernel(
        const float* __restrict__ conp, const float* __restrict__ conh,
        float* __restrict__ meanv, float* __restrict__ maxv) {
    int blk = blockIdx.x;
    int sh = blk & 1;
    int sdb = blk >> 1;
    int b = sdb & 31, sd = sdb >> 5;
    int dir = sd & 1, side = sd >> 1;
    int t = threadIdx.x;
    __shared__ __hip_bfloat16 AT[32 * KST];   // 14.8 KB self rows (bf16)
    __shared__ __hip_bfloat16 BT[64 * KST];   // 29.7 KB opp rows (bf16)
    __shared__ float S_L[32 * SST];           // 8.7 KB normalized att slice
    __shared__ float nrmA[32], nrmB[64], dsum[32];

    if (t < 32) nrmA[t] = 0.f;
    if (t < 64) nrmB[t] = 0.f;
    __syncthreads();

    const float* selfb = side ? conh : conp;
    const float* oppb  = side ? conp : conh;

    // stage A (self, 32 rows) + accumulate row sumsq
    for (int e = t; e < 32 * 28; e += 256) {
        int sl = e / 28, ck = e % 28, k = ck * 8;
        __align__(16) __hip_bfloat16 r8[8];
        if (k < HH) {
            const float* xp = selfb + (b * SS + sh * 32 + sl) * (2 * HH) + dir * HH + k;
            float xv[8];
            *(float4*)&xv[0] = *(const float4*)xp; *(float4*)&xv[4] = *(const float4*)(xp + 4);
            float ss = 0.f;
#pragma unroll
            for (int i = 0; i < 8; ++i) { r8[i] = __float2bfloat16(xv[i]); ss = fmaf(xv[i], xv[i], ss); }
            atomicAdd(&nrmA[sl], ss);
        } else {
#pragma unroll
            for (int i = 0; i < 8; ++i) r8[i] = __float2bfloat16(0.f);
        }
        *(bf16x8*)&AT[sl * KST + k] = *(bf16x8*)r8;
    }
    // stage B (opp, 64 rows) + accumulate row sumsq
    for (int e = t; e < 64 * 28; e += 256) {
        int rw = e / 28, ck = e % 28, k = ck * 8;
        __align__(16) __hip_bfloat16 r8[8];
        if (k < HH) {
            const float* xp = oppb + (b * SS + rw) * (2 * HH) + dir * HH + k;
            float xv[8];
            *(float4*)&xv[0] = *(const float4*)xp; *(float4*)&xv[4] = *(const float4*)(xp + 4);
            float ss = 0.f;
#pragma unroll
            for (int i = 0; i < 8; ++i) { r8[i] = __float2bfloat16(xv[i]); ss = fmaf(xv[i], xv[i], ss); }
            atomicAdd(&nrmB[rw], ss);
        } else {
#pragma unroll
            for (int i = 0; i < 8; ++i) r8[i] = __float2bfloat16(0.f);
        }
        *(bf16x8*)&BT[rw * KST + k] = *(bf16x8*)r8;
    }
    __syncthreads();

    // MFMA: S = A @ B^T (32x64), wave w: row tile rt = w&1, col tiles ct = (w>>1)*2 + {0,1}
    int wv_ = __builtin_amdgcn_readfirstlane(t >> 6);
    int lane = t & 63;
    int q = lane >> 4, c = lane & 15;
    int rt = wv_ & 1, cth = wv_ >> 1;

    f32x4 acc[2];
    acc[0] = (f32x4){0.f, 0.f, 0.f, 0.f};
    acc[1] = (f32x4){0.f, 0.f, 0.f, 0.f};
    for (int ks = 0; ks < 7; ++ks) {
        int kb = ks * 32 + q * 8;
        bf16x8 af = *(const bf16x8*)&AT[(rt * 16 + c) * KST + kb];
#pragma unroll
        for (int i = 0; i < 2; ++i) {
            int ct = cth * 2 + i;
            bf16x8 bf_ = *(const bf16x8*)&BT[(ct * 16 + c) * KST + kb];
            acc[i] = __builtin_amdgcn_mfma_f32_16x16x32_bf16(af, bf_, acc[i], 0, 0, 0);
        }
    }
    // normalize + store S tile
#pragma unroll
    for (int i = 0; i < 2; ++i) {
        int col = (cth * 2 + i) * 16 + c;
        float no = sqrtf(nrmB[col]);
#pragma unroll
        for (int r = 0; r < 4; ++r) {
            int row = rt * 16 + q * 4 + r;
            float ns = sqrtf(nrmA[row]);
            S_L[row * SST + col] = acc[i][r] / fmaxf(ns * no, EPS);
        }
    }
    __syncthreads();

    // phase 2: row sums (mean denominator; == reference row/col att-sum per side)
    if (t < 32) {
        float sm = 0.f;
        for (int k = 0; k < 64; ++k) sm += S_L[t * SST + k];
        dsum[t] = fmaxf(sm, EPS);
    }
    __syncthreads();

    // phase 3: mean & max vectors
    for (int e = t; e < 32 * 25; e += 256) {
        int s = e / 25, hc = e % 25, h0 = hc * 8;
        float dsv = dsum[s];
        float ms[8], mx[8];
#pragma unroll
        for (int i = 0; i < 8; ++i) { ms[i] = 0.f; mx[i] = -INFINITY; }
        for (int k = 0; k < 64; ++k) {
            float a = S_L[s * SST + k];
            bf16x8 ov = *(const bf16x8*)&BT[k * KST + h0];
#pragma unroll
            for (int i = 0; i < 8; ++i) {
                float tt = a * bf2f(ov[i]);
                ms[i] += tt;
                mx[i] = fmaxf(mx[i], tt);
            }
        }
        int obase = ((sd * BB + b) * SS + sh * 32 + s) * HH + h0;
#pragma unroll
        for (int i = 0; i < 8; ++i) ms[i] /= dsv;
        *(float4*)&meanv[obase]     = *(float4*)&ms[0];
        *(float4*)&meanv[obase + 4] = *(float4*)&ms[4];
        *(float4*)&maxv[obase]      = *(float4*)&mx[0];
        *(float4*)&maxv[obase + 4]  = *(float4*)&mx[4];
    }
}

// ---------------------------------------------------------------- mp_match v5: bf16 MFMA
__global__ __launch_bounds__(256) void match_kernel(
        const float* __restrict__ conp, const float* __restrict__ conh,
        const float* __restrict__ meanv, const float* __restrict__ maxv,
        const float* __restrict__ w1, const float* __restrict__ w2,
        const float* __restrict__ w5, const float* __restrict__ w6,
        const float* __restrict__ w7, const float* __restrict__ w8,
        float* __restrict__ out) {
    int blk = blockIdx.x;
    int sh = blk & 1;
    int r_ = blk >> 1;
    int m = r_ % 3;
    int sdb = r_ / 3;
    int b = sdb & 31, sd = sdb >> 5;
    int dir = sd & 1, side = sd >> 1;
    int t = threadIdx.x;
    __shared__ __hip_bfloat16 AT[96 * KST];
    __shared__ __hip_bfloat16 BT[32 * KST];

    const float* wsrc = (m == 0) ? (dir ? w2 : w1)
                      : (m == 1) ? (dir ? w6 : w5)
                                 : (dir ? w8 : w7);
    const float* xbase = side ? conh : conp;
    const float* opp   = side ? conp : conh;
    int fidx = dir ? 0 : (SS - 1);
    const float* fvr = opp + (b * SS + fidx) * (2 * HH) + dir * HH;

    for (int e = t; e < 32 * 28; e += 256) {
        int sl = e / 28, ck = e % 28;
        int k = ck * 8;
        int s = sh * 32 + sl;
        __align__(16) __hip_bfloat16 r0[8], r1[8], r2[8];
        if (k < HH) {
            const float* xp = xbase + (b * SS + s) * (2 * HH) + dir * HH + k;
            const float* yp = (m == 0) ? (fvr + k)
                            : ((m == 1 ? meanv : maxv) + ((sd * BB + b) * SS + s) * HH + k);
            float xv[8], yv[8];
            *(float4*)&xv[0] = *(const float4*)xp; *(float4*)&xv[4] = *(const float4*)(xp + 4);
            *(float4*)&yv[0] = *(const float4*)yp; *(float4*)&yv[4] = *(const float4*)(yp + 4);
#pragma unroll
            for (int i = 0; i < 8; ++i) {
                r0[i] = __float2bfloat16(xv[i] * xv[i]);
                r1[i] = __float2bfloat16(xv[i] * yv[i]);
                r2[i] = __float2bfloat16(yv[i] * yv[i]);
            }
        } else {
#pragma unroll
            for (int i = 0; i < 8; ++i) {
                r0[i] = __float2bfloat16(0.f); r1[i] = __float2bfloat16(0.f); r2[i] = __float2bfloat16(0.f);
            }
        }
        *(bf16x8*)&AT[(0 * 32 + sl) * KST + k] = *(bf16x8*)r0;
        *(bf16x8*)&AT[(1 * 32 + sl) * KST + k] = *(bf16x8*)r1;
        *(bf16x8*)&AT[(2 * 32 + sl) * KST + k] = *(bf16x8*)r2;
    }
    for (int e = t; e < 32 * 28; e += 256) {
        int l = e / 28, ck = e % 28;
        int k = ck * 8;
        __align__(16) __hip_bfloat16 wr[8];
        if (l < LL && k < HH) {
            const float* wp = wsrc + l * HH + k;
            float wv[8];
            *(float4*)&wv[0] = *(const float4*)wp; *(float4*)&wv[4] = *(const float4*)(wp + 4);
#pragma unroll
            for (int i = 0; i < 8; ++i) wr[i] = __float2bfloat16(wv[i] * wv[i]);
        } else {
#pragma unroll
            for (int i = 0; i < 8; ++i) wr[i] = __float2bfloat16(0.f);
        }
        *(bf16x8*)&BT[l * KST + k] = *(bf16x8*)wr;
    }
    __syncthreads();

    int wv_ = __builtin_amdgcn_readfirstlane(t >> 6);
    int lane = t & 63;
    int q = lane >> 4, c = lane & 15;
    int slh = wv_ >> 1, ntile = wv_ & 1;

    f32x4 accA = (f32x4){0.f, 0.f, 0.f, 0.f};
    f32x4 accD = (f32x4){0.f, 0.f, 0.f, 0.f};
    f32x4 accB = (f32x4){0.f, 0.f, 0.f, 0.f};
    for (int ks = 0; ks < 7; ++ks) {
        int kb = ks * 32 + q * 8;
        bf16x8 bf = *(const bf16x8*)&BT[(ntile * 16 + c) * KST + kb];
        bf16x8 a0 = *(const bf16x8*)&AT[(0 * 32 + slh * 16 + c) * KST + kb];
        bf16x8 a1 = *(const bf16x8*)&AT[(1 * 32 + slh * 16 + c) * KST + kb];
        bf16x8 a2 = *(const bf16x8*)&AT[(2 * 32 + slh * 16 + c) * KST + kb];
        accA = __builtin_amdgcn_mfma_f32_16x16x32_bf16(a0, bf, accA, 0, 0, 0);
        accD = __builtin_amdgcn_mfma_f32_16x16x32_bf16(a1, bf, accD, 0, 0, 0);
        accB = __builtin_amdgcn_mfma_f32_16x16x32_bf16(a2, bf, accB, 0, 0, 0);
    }

    int l = ntile * 16 + c;
    if (l < LL) {
        int chunk = (m == 0) ? 0 : (m == 1) ? 40 : 60;
#pragma unroll
        for (int r = 0; r < 4; ++r) {
            int s = sh * 32 + slh * 16 + q * 4 + r;
            float cosv = accD[r] / fmaxf(sqrtf(accA[r] * accB[r]), EPS);
            out[side * (BB * SS * 160) + (b * SS + s) * 160 + dir * 80 + chunk + l] = cosv;
        }
    }
}

// ---------------------------------------------------------------- pairwise via bf16 MFMA
__global__ __launch_bounds__(256) void pairmfma_kernel(
        const float* __restrict__ conp, const float* __restrict__ conh,
        const float* __restrict__ w3, const float* __restrict__ w4,
        const float* __restrict__ wn, float* __restrict__ out) {
    int blk = blockIdx.x;
    int l = blk % LL; int db = blk / LL; int b = db & 31; int dir = db >> 5;
    int t = threadIdx.x;
    __shared__ __hip_bfloat16 AT[64 * KST];
    __shared__ __hip_bfloat16 BT[64 * KST];
    __shared__ float cmL[4 * 64];

    const float* wrow = (dir ? w4 : w3) + l * HH;
    const float* Ag = conp + dir * HH;
    const float* Bg = conh + dir * HH;

    for (int e = t; e < 64 * 28; e += 256) {
        int m = e / 28, ck = e - m * 28;
        int k = ck * 8;
        __align__(16) __hip_bfloat16 at8[8];
        __align__(16) __hip_bfloat16 bt8[8];
        if (k < HH) {
            const float* ap = Ag + (b * SS + m) * (2 * HH) + k;
            const float* bp = Bg + (b * SS + m) * (2 * HH) + k;
            const float* wp = wrow + k;
            float4 a0 = *(const float4*)ap, a1 = *(const float4*)(ap + 4);
            float4 b0 = *(const float4*)bp, b1 = *(const float4*)(bp + 4);
            float4 w0 = *(const float4*)wp, w1 = *(const float4*)(wp + 4);
            at8[0] = __float2bfloat16(a0.x * w0.x); at8[1] = __float2bfloat16(a0.y * w0.y);
            at8[2] = __float2bfloat16(a0.z * w0.z); at8[3] = __float2bfloat16(a0.w * w0.w);
            at8[4] = __float2bfloat16(a1.x * w1.x); at8[5] = __float2bfloat16(a1.y * w1.y);
            at8[6] = __float2bfloat16(a1.z * w1.z); at8[7] = __float2bfloat16(a1.w * w1.w);
            bt8[0] = __float2bfloat16(b0.x * w0.x); bt8[1] = __float2bfloat16(b0.y * w0.y);
            bt8[2] = __float2bfloat16(b0.z * w0.z); bt8[3] = __float2bfloat16(b0.w * w0.w);
            bt8[4] = __float2bfloat16(b1.x * w1.x); bt8[5] = __float2bfloat16(b1.y * w1.y);
            bt8[6] = __float2bfloat16(b1.z * w1.z); bt8[7] = __float2bfloat16(b1.w * w1.w);
        } else {
#pragma unroll
            for (int ii = 0; ii < 8; ++ii) { at8[ii] = __float2bfloat16(0.f); bt8[ii] = __float2bfloat16(0.f); }
        }
        *(bf16x8*)&AT[m * KST + k] = *(bf16x8*)at8;
        *(bf16x8*)&BT[m * KST + k] = *(bf16x8*)bt8;
    }
    __syncthreads();

    int wv_ = __builtin_amdgcn_readfirstlane(t >> 6);
    int lane = t & 63;
    int q = lane >> 4, c = lane & 15;
    int m0 = wv_ * 16;

    f32x4 acc[4];
#pragma unroll
    for (int ct = 0; ct < 4; ++ct) acc[ct] = (f32x4){0.f, 0.f, 0.f, 0.f};

    for (int ks = 0; ks < 7; ++ks) {
        int kb = ks * 32 + q * 8;
        bf16x8 af = *(const bf16x8*)&AT[(m0 + c) * KST + kb];
#pragma unroll
        for (int ct = 0; ct < 4; ++ct) {
            bf16x8 bf_ = *(const bf16x8*)&BT[(ct * 16 + c) * KST + kb];
            acc[ct] = __builtin_amdgcn_mfma_f32_16x16x32_bf16(af, bf_, acc[ct], 0, 0, 0);
        }
    }

    float na[4], nb[4];
#pragma unroll
    for (int r = 0; r < 4; ++r) {
        int i = m0 + q * 4 + r;
        na[r] = wn[(((0 * 2 + dir) * BB + b) * SS + i) * LL + l];
    }
#pragma unroll
    for (int ct = 0; ct < 4; ++ct) {
        int j = ct * 16 + c;
        nb[ct] = wn[(((1 * 2 + dir) * BB + b) * SS + j) * LL + l];
    }

    float rowm[4] = {-INFINITY, -INFINITY, -INFINITY, -INFINITY};
    float colm[4] = {-INFINITY, -INFINITY, -INFINITY, -INFINITY};
#pragma unroll
    for (int ct = 0; ct < 4; ++ct) {
#pragma unroll
        for (int r = 0; r < 4; ++r) {
            float cv = acc[ct][r] / fmaxf(na[r] * nb[ct], EPS);
            rowm[r] = fmaxf(rowm[r], cv);
            colm[ct] = fmaxf(colm[ct], cv);
        }
    }

#pragma unroll
    for (int r = 0; r < 4; ++r) {
        float v = rowm[r];
        v = fmaxf(v, __shfl_xor(v, 1, 64));
        v = fmaxf(v, __shfl_xor(v, 2, 64));
        v = fmaxf(v, __shfl_xor(v, 4, 64));
        v = fmaxf(v, __shfl_xor(v, 8, 64));
        rowm[r] = v;
    }
    if (c == 0) {
#pragma unroll
        for (int r = 0; r < 4; ++r) {
            int i = m0 + q * 4 + r;
            out[(b * SS + i) * 160 + dir * 80 + 20 + l] = rowm[r];
        }
    }

#pragma unroll
    for (int ct = 0; ct < 4; ++ct) {
        float v = colm[ct];
        v = fmaxf(v, __shfl_xor(v, 16, 64));
        v = fmaxf(v, __shfl_xor(v, 32, 64));
        colm[ct] = v;
    }
    if (q == 0) {
#pragma unroll
        for (int ct = 0; ct < 4; ++ct) cmL[wv_ * 64 + ct * 16 + c] = colm[ct];
    }
    __syncthreads();
    if (t < 64) {
        float m = fmaxf(fmaxf(cmL[t], cmL[64 + t]), fmaxf(cmL[128 + t], cmL[192 + t]));
        out[BB * SS * 160 + (b * SS + t) * 160 + dir * 80 + 20 + l] = m;
    }
}

extern "C" void kernel_launch(void* const* d_in, const int* in_sizes, int n_in,
                              void* d_out, int out_size, void* d_ws, size_t ws_size,
                              hipStream_t stream) {
    const float* conp = (const float*)d_in[0];
    const float* conh = (const float*)d_in[1];
    const float* w1 = (const float*)d_in[2];
    const float* w2 = (const float*)d_in[3];
    const float* w3 = (const float*)d_in[4];
    const float* w4 = (const float*)d_in[5];
    const float* w5 = (const float*)d_in[6];
    const float* w6 = (const float*)d_in[7];
    const float* w7 = (const float*)d_in[8];
    const float* w8 = (const float*)d_in[9];
    float* out = (float*)d_out;
    float* ws  = (float*)d_ws;

    float* wn     = ws;                        // 163840
    float* meanv  = wn + 4 * BB * SS * LL;     // 1638400
    float* maxv   = meanv + 4 * BB * SS * HH;  // 1638400

    prep_kernel<<<256, 256, 0, stream>>>(conp, conh, w3, w4, wn);
    attfused_kernel<<<4 * BB * 2, 256, 0, stream>>>(conp, conh, meanv, maxv);
    match_kernel<<<4 * BB * 3 * 2, 256, 0, stream>>>(conp, conh, meanv, maxv,
                                                     w1, w2, w5, w6, w7, w8, out);
    pairmfma_kernel<<<2 * BB * LL, 256, 0, stream>>>(conp, conh, w3, w4, wn, out);
}

// Round 15
// 123.546 us; speedup vs baseline: 2.0295x; 1.1144x over previous
//
#include <hip/hip_runtime.h>
#include <hip/hip_bf16.h>
#include <math.h>

#define EPS 1e-8f
#define BB 32
#define SS 64
#define HH 200
#define LL 20
#define KP 224    // K padded to 7*32
#define KST 232   // LDS row stride (bf16 elems), 16B-aligned, good bank spread
#define MST 204   // prep LDS row stride (floats)
#define SST 68    // att S-tile LDS row stride (floats)

typedef short bf16x8 __attribute__((ext_vector_type(8)));
typedef float f32x4 __attribute__((ext_vector_type(4)));

__device__ inline float bf2f(short u) {
    union { unsigned int i; float f; } v;
    v.i = ((unsigned int)(unsigned short)u) << 16;
    return v.f;
}

// ws layout (floats): wn 163840 | meanv 1638400 | maxv 1638400

// ================================================================ kernel 1: prep + attfused
// blocks [0,256): wn (prep); blocks [256,512): fused att+attvec. 512 threads.
__global__ __launch_bounds__(512) void fused1_kernel(
        const float* __restrict__ conp, const float* __restrict__ conh,
        const float* __restrict__ w3, const float* __restrict__ w4,
        float* __restrict__ wn, float* __restrict__ meanv, float* __restrict__ maxv) {
    __shared__ __align__(16) float smem[13440];   // 53.8 KB union
    int t = threadIdx.x;

    if (blockIdx.x < 256) {
        // ---------------- prep: pairwise weighted norms wn
        float* w2L = smem;          // LL*MST = 4080
        float* x2L = smem + 4080;   // 32*MST = 6528
        int wnb = blockIdx.x;
        int sh = wnb & 1, sdb = wnb >> 1;
        int b = sdb & 31, sd = sdb >> 5;
        int dir = sd & 1, side = sd >> 1;
        const float* wsrc = dir ? w4 : w3;
        for (int e = t; e < LL * 25; e += 512) {
            int l = e / 25, c = e % 25, h0 = c * 8;
            float4 u0 = *(const float4*)(wsrc + l * HH + h0);
            float4 u1 = *(const float4*)(wsrc + l * HH + h0 + 4);
            *(float4*)&w2L[l * MST + h0]     = make_float4(u0.x * u0.x, u0.y * u0.y, u0.z * u0.z, u0.w * u0.w);
            *(float4*)&w2L[l * MST + h0 + 4] = make_float4(u1.x * u1.x, u1.y * u1.y, u1.z * u1.z, u1.w * u1.w);
        }
        const float* xbase = side ? conh : conp;
        for (int e = t; e < 32 * 25; e += 512) {
            int s_ = e / 25, c = e % 25, h0 = c * 8;
            const float* xp = xbase + (b * SS + sh * 32 + s_) * (2 * HH) + dir * HH + h0;
            float4 u0 = *(const float4*)xp;
            float4 u1 = *(const float4*)(xp + 4);
            *(float4*)&x2L[s_ * MST + h0]     = make_float4(u0.x * u0.x, u0.y * u0.y, u0.z * u0.z, u0.w * u0.w);
            *(float4*)&x2L[s_ * MST + h0 + 4] = make_float4(u1.x * u1.x, u1.y * u1.y, u1.z * u1.z, u1.w * u1.w);
        }
        __syncthreads();
        for (int o = t; o < 32 * LL; o += 512) {
            int s_ = o / LL, l = o % LL;
            const float4* xp = (const float4*)&x2L[s_ * MST];
            const float4* wp = (const float4*)&w2L[l * MST];
            float a0 = 0.f, a1 = 0.f, a2 = 0.f, a3 = 0.f;
            for (int h4 = 0; h4 < 50; ++h4) {
                float4 x = xp[h4]; float4 w = wp[h4];
                a0 = fmaf(x.x, w.x, a0); a1 = fmaf(x.y, w.y, a1);
                a2 = fmaf(x.z, w.z, a2); a3 = fmaf(x.w, w.w, a3);
            }
            wn[((sd * BB + b) * SS + sh * 32 + s_) * LL + l] = sqrtf(a0 + a1 + a2 + a3);
        }
    } else {
        // ---------------- fused att + attvec
        __hip_bfloat16* AT = (__hip_bfloat16*)smem;            // 32*KST bf16 (3712 fl)
        __hip_bfloat16* BT = (__hip_bfloat16*)(smem + 3712);   // 64*KST bf16 (7424 fl)
        float* S_L  = smem + 3712 + 7424;                      // 32*SST = 2176
        float* nrmA = S_L + 32 * SST;                          // 32
        float* nrmB = nrmA + 32;                               // 64
        float* dsum = nrmB + 64;                               // 32

        int blk = blockIdx.x - 256;
        int sh = blk & 1;
        int sdb = blk >> 1;
        int b = sdb & 31, sd = sdb >> 5;
        int dir = sd & 1, side = sd >> 1;

        if (t < 32) nrmA[t] = 0.f;
        if (t < 64) nrmB[t] = 0.f;
        __syncthreads();

        const float* selfb = side ? conh : conp;
        const float* oppb  = side ? conp : conh;

        for (int e = t; e < 32 * 28; e += 512) {
            int sl = e / 28, ck = e % 28, k = ck * 8;
            __align__(16) __hip_bfloat16 r8[8];
            if (k < HH) {
                const float* xp = selfb + (b * SS + sh * 32 + sl) * (2 * HH) + dir * HH + k;
                float xv[8];
                *(float4*)&xv[0] = *(const float4*)xp; *(float4*)&xv[4] = *(const float4*)(xp + 4);
                float ss = 0.f;
#pragma unroll
                for (int i = 0; i < 8; ++i) { r8[i] = __float2bfloat16(xv[i]); ss = fmaf(xv[i], xv[i], ss); }
                atomicAdd(&nrmA[sl], ss);
            } else {
#pragma unroll
                for (int i = 0; i < 8; ++i) r8[i] = __float2bfloat16(0.f);
            }
            *(bf16x8*)&AT[sl * KST + k] = *(bf16x8*)r8;
        }
        for (int e = t; e < 64 * 28; e += 512) {
            int rw = e / 28, ck = e % 28, k = ck * 8;
            __align__(16) __hip_bfloat16 r8[8];
            if (k < HH) {
                const float* xp = oppb + (b * SS + rw) * (2 * HH) + dir * HH + k;
                float xv[8];
                *(float4*)&xv[0] = *(const float4*)xp; *(float4*)&xv[4] = *(const float4*)(xp + 4);
                float ss = 0.f;
#pragma unroll
                for (int i = 0; i < 8; ++i) { r8[i] = __float2bfloat16(xv[i]); ss = fmaf(xv[i], xv[i], ss); }
                atomicAdd(&nrmB[rw], ss);
            } else {
#pragma unroll
                for (int i = 0; i < 8; ++i) r8[i] = __float2bfloat16(0.f);
            }
            *(bf16x8*)&BT[rw * KST + k] = *(bf16x8*)r8;
        }
        __syncthreads();

        // MFMA: S = A @ B^T (32x64). 8 waves, one 16x16 tile each: rt = w&1, ct = w>>1.
        int wv_ = __builtin_amdgcn_readfirstlane(t >> 6);
        int lane = t & 63;
        int q = lane >> 4, c = lane & 15;
        int rt = wv_ & 1, ct = wv_ >> 1;

        f32x4 acc = (f32x4){0.f, 0.f, 0.f, 0.f};
        for (int ks = 0; ks < 7; ++ks) {
            int kb = ks * 32 + q * 8;
            bf16x8 af  = *(const bf16x8*)&AT[(rt * 16 + c) * KST + kb];
            bf16x8 bf_ = *(const bf16x8*)&BT[(ct * 16 + c) * KST + kb];
            acc = __builtin_amdgcn_mfma_f32_16x16x32_bf16(af, bf_, acc, 0, 0, 0);
        }
        {
            int col = ct * 16 + c;
            float no = sqrtf(nrmB[col]);
#pragma unroll
            for (int r = 0; r < 4; ++r) {
                int row = rt * 16 + q * 4 + r;
                float ns = sqrtf(nrmA[row]);
                S_L[row * SST + col] = acc[r] / fmaxf(ns * no, EPS);
            }
        }
        __syncthreads();

        if (t < 32) {
            float sm = 0.f;
            for (int k = 0; k < 64; ++k) sm += S_L[t * SST + k];
            dsum[t] = fmaxf(sm, EPS);
        }
        __syncthreads();

        for (int e = t; e < 32 * 25; e += 512) {
            int s = e / 25, hc = e % 25, h0 = hc * 8;
            float dsv = dsum[s];
            float ms[8], mx[8];
#pragma unroll
            for (int i = 0; i < 8; ++i) { ms[i] = 0.f; mx[i] = -INFINITY; }
            for (int k = 0; k < 64; ++k) {
                float a = S_L[s * SST + k];
                bf16x8 ov = *(const bf16x8*)&BT[k * KST + h0];
#pragma unroll
                for (int i = 0; i < 8; ++i) {
                    float tt = a * bf2f(ov[i]);
                    ms[i] += tt;
                    mx[i] = fmaxf(mx[i], tt);
                }
            }
            int obase = ((sd * BB + b) * SS + sh * 32 + s) * HH + h0;
#pragma unroll
            for (int i = 0; i < 8; ++i) ms[i] /= dsv;
            *(float4*)&meanv[obase]     = *(float4*)&ms[0];
            *(float4*)&meanv[obase + 4] = *(float4*)&ms[4];
            *(float4*)&maxv[obase]      = *(float4*)&mx[0];
            *(float4*)&maxv[obase + 4]  = *(float4*)&mx[4];
        }
    }
}

// ================================================================ kernel 2: match + pairmfma
// blocks [0,768): mp_match v5; blocks [768,2048): pairwise MFMA. 256 threads.
// (r14 bug: match section sized 1536 -> side up to 3 -> OOB out writes -> abort)
__global__ __launch_bounds__(256) void fused2_kernel(
        const float* __restrict__ conp, const float* __restrict__ conh,
        const float* __restrict__ meanv, const float* __restrict__ maxv,
        const float* __restrict__ w1, const float* __restrict__ w2,
        const float* __restrict__ w3, const float* __restrict__ w4,
        const float* __restrict__ w5, const float* __restrict__ w6,
        const float* __restrict__ w7, const float* __restrict__ w8,
        const float* __restrict__ wn, float* __restrict__ out) {
    __shared__ __align__(16) float smem[15104];   // 59 KB union
    int t = threadIdx.x;

    if (blockIdx.x < 768) {
        // ---------------- mp_match v5 (bf16 MFMA)
        __hip_bfloat16* AT = (__hip_bfloat16*)smem;             // 96*KST bf16 (11136 fl)
        __hip_bfloat16* BT = (__hip_bfloat16*)(smem + 11136);   // 32*KST bf16 (3712 fl)
        int blk = blockIdx.x;
        int sh = blk & 1;
        int r_ = blk >> 1;
        int m = r_ % 3;
        int sdb = r_ / 3;
        int b = sdb & 31, sd = sdb >> 5;
        int dir = sd & 1, side = sd >> 1;

        const float* wsrc = (m == 0) ? (dir ? w2 : w1)
                          : (m == 1) ? (dir ? w6 : w5)
                                     : (dir ? w8 : w7);
        const float* xbase = side ? conh : conp;
        const float* opp   = side ? conp : conh;
        int fidx = dir ? 0 : (SS - 1);
        const float* fvr = opp + (b * SS + fidx) * (2 * HH) + dir * HH;

        for (int e = t; e < 32 * 28; e += 256) {
            int sl = e / 28, ck = e % 28;
            int k = ck * 8;
            int s = sh * 32 + sl;
            __align__(16) __hip_bfloat16 r0[8], r1[8], r2[8];
            if (k < HH) {
                const float* xp = xbase + (b * SS + s) * (2 * HH) + dir * HH + k;
                const float* yp = (m == 0) ? (fvr + k)
                                : ((m == 1 ? meanv : maxv) + ((sd * BB + b) * SS + s) * HH + k);
                float xv[8], yv[8];
                *(float4*)&xv[0] = *(const float4*)xp; *(float4*)&xv[4] = *(const float4*)(xp + 4);
                *(float4*)&yv[0] = *(const float4*)yp; *(float4*)&yv[4] = *(const float4*)(yp + 4);
#pragma unroll
                for (int i = 0; i < 8; ++i) {
                    r0[i] = __float2bfloat16(xv[i] * xv[i]);
                    r1[i] = __float2bfloat16(xv[i] * yv[i]);
                    r2[i] = __float2bfloat16(yv[i] * yv[i]);
                }
            } else {
#pragma unroll
                for (int i = 0; i < 8; ++i) {
                    r0[i] = __float2bfloat16(0.f); r1[i] = __float2bfloat16(0.f); r2[i] = __float2bfloat16(0.f);
                }
            }
            *(bf16x8*)&AT[(0 * 32 + sl) * KST + k] = *(bf16x8*)r0;
            *(bf16x8*)&AT[(1 * 32 + sl) * KST + k] = *(bf16x8*)r1;
            *(bf16x8*)&AT[(2 * 32 + sl) * KST + k] = *(bf16x8*)r2;
        }
        for (int e = t; e < 32 * 28; e += 256) {
            int l = e / 28, ck = e % 28;
            int k = ck * 8;
            __align__(16) __hip_bfloat16 wr[8];
            if (l < LL && k < HH) {
                const float* wp = wsrc + l * HH + k;
                float wv[8];
                *(float4*)&wv[0] = *(const float4*)wp; *(float4*)&wv[4] = *(const float4*)(wp + 4);
#pragma unroll
                for (int i = 0; i < 8; ++i) wr[i] = __float2bfloat16(wv[i] * wv[i]);
            } else {
#pragma unroll
                for (int i = 0; i < 8; ++i) wr[i] = __float2bfloat16(0.f);
            }
            *(bf16x8*)&BT[l * KST + k] = *(bf16x8*)wr;
        }
        __syncthreads();

        int wv_ = __builtin_amdgcn_readfirstlane(t >> 6);
        int lane = t & 63;
        int q = lane >> 4, c = lane & 15;
        int slh = wv_ >> 1, ntile = wv_ & 1;

        f32x4 accA = (f32x4){0.f, 0.f, 0.f, 0.f};
        f32x4 accD = (f32x4){0.f, 0.f, 0.f, 0.f};
        f32x4 accB = (f32x4){0.f, 0.f, 0.f, 0.f};
        for (int ks = 0; ks < 7; ++ks) {
            int kb = ks * 32 + q * 8;
            bf16x8 bf = *(const bf16x8*)&BT[(ntile * 16 + c) * KST + kb];
            bf16x8 a0 = *(const bf16x8*)&AT[(0 * 32 + slh * 16 + c) * KST + kb];
            bf16x8 a1 = *(const bf16x8*)&AT[(1 * 32 + slh * 16 + c) * KST + kb];
            bf16x8 a2 = *(const bf16x8*)&AT[(2 * 32 + slh * 16 + c) * KST + kb];
            accA = __builtin_amdgcn_mfma_f32_16x16x32_bf16(a0, bf, accA, 0, 0, 0);
            accD = __builtin_amdgcn_mfma_f32_16x16x32_bf16(a1, bf, accD, 0, 0, 0);
            accB = __builtin_amdgcn_mfma_f32_16x16x32_bf16(a2, bf, accB, 0, 0, 0);
        }

        int l = ntile * 16 + c;
        if (l < LL) {
            int chunk = (m == 0) ? 0 : (m == 1) ? 40 : 60;
#pragma unroll
            for (int r = 0; r < 4; ++r) {
                int s = sh * 32 + slh * 16 + q * 4 + r;
                float cosv = accD[r] / fmaxf(sqrtf(accA[r] * accB[r]), EPS);
                out[side * (BB * SS * 160) + (b * SS + s) * 160 + dir * 80 + chunk + l] = cosv;
            }
        }
    } else {
        // ---------------- pairwise bf16 MFMA
        __hip_bfloat16* AT = (__hip_bfloat16*)smem;            // 64*KST bf16 (7424 fl)
        __hip_bfloat16* BT = (__hip_bfloat16*)(smem + 7424);   // 64*KST bf16 (7424 fl)
        float* cmL = smem + 14848;                             // 256 fl
        int blk = blockIdx.x - 768;
        int l = blk % LL; int db = blk / LL; int b = db & 31; int dir = db >> 5;

        const float* wrow = (dir ? w4 : w3) + l * HH;
        const float* Ag = conp + dir * HH;
        const float* Bg = conh + dir * HH;

        for (int e = t; e < 64 * 28; e += 256) {
            int m = e / 28, ck = e - m * 28;
            int k = ck * 8;
            __align__(16) __hip_bfloat16 at8[8];
            __align__(16) __hip_bfloat16 bt8[8];
            if (k < HH) {
                const float* ap = Ag + (b * SS + m) * (2 * HH) + k;
                const float* bp = Bg + (b * SS + m) * (2 * HH) + k;
                const float* wp = wrow + k;
                float4 a0 = *(const float4*)ap, a1 = *(const float4*)(ap + 4);
                float4 b0 = *(const float4*)bp, b1 = *(const float4*)(bp + 4);
                float4 w0 = *(const float4*)wp, w1 = *(const float4*)(wp + 4);
                at8[0] = __float2bfloat16(a0.x * w0.x); at8[1] = __float2bfloat16(a0.y * w0.y);
                at8[2] = __float2bfloat16(a0.z * w0.z); at8[3] = __float2bfloat16(a0.w * w0.w);
                at8[4] = __float2bfloat16(a1.x * w1.x); at8[5] = __float2bfloat16(a1.y * w1.y);
                at8[6] = __float2bfloat16(a1.z * w1.z); at8[7] = __float2bfloat16(a1.w * w1.w);
                bt8[0] = __float2bfloat16(b0.x * w0.x); bt8[1] = __float2bfloat16(b0.y * w0.y);
                bt8[2] = __float2bfloat16(b0.z * w0.z); bt8[3] = __float2bfloat16(b0.w * w0.w);
                bt8[4] = __float2bfloat16(b1.x * w1.x); bt8[5] = __float2bfloat16(b1.y * w1.y);
                bt8[6] = __float2bfloat16(b1.z * w1.z); bt8[7] = __float2bfloat16(b1.w * w1.w);
            } else {
#pragma unroll
                for (int ii = 0; ii < 8; ++ii) { at8[ii] = __float2bfloat16(0.f); bt8[ii] = __float2bfloat16(0.f); }
            }
            *(bf16x8*)&AT[m * KST + k] = *(bf16x8*)at8;
            *(bf16x8*)&BT[m * KST + k] = *(bf16x8*)bt8;
        }
        __syncthreads();

        int wv_ = __builtin_amdgcn_readfirstlane(t >> 6);
        int lane = t & 63;
        int q = lane >> 4, c = lane & 15;
        int m0 = wv_ * 16;

        f32x4 acc[4];
#pragma unroll
        for (int ct = 0; ct < 4; ++ct) acc[ct] = (f32x4){0.f, 0.f, 0.f, 0.f};

        for (int ks = 0; ks < 7; ++ks) {
            int kb = ks * 32 + q * 8;
            bf16x8 af = *(const bf16x8*)&AT[(m0 + c) * KST + kb];
#pragma unroll
            for (int ct = 0; ct < 4; ++ct) {
                bf16x8 bf_ = *(const bf16x8*)&BT[(ct * 16 + c) * KST + kb];
                acc[ct] = __builtin_amdgcn_mfma_f32_16x16x32_bf16(af, bf_, acc[ct], 0, 0, 0);
            }
        }

        float na[4], nb[4];
#pragma unroll
        for (int r = 0; r < 4; ++r) {
            int i = m0 + q * 4 + r;
            na[r] = wn[(((0 * 2 + dir) * BB + b) * SS + i) * LL + l];
        }
#pragma unroll
        for (int ct = 0; ct < 4; ++ct) {
            int j = ct * 16 + c;
            nb[ct] = wn[(((1 * 2 + dir) * BB + b) * SS + j) * LL + l];
        }

        float rowm[4] = {-INFINITY, -INFINITY, -INFINITY, -INFINITY};
        float colm[4] = {-INFINITY, -INFINITY, -INFINITY, -INFINITY};
#pragma unroll
        for (int ct = 0; ct < 4; ++ct) {
#pragma unroll
            for (int r = 0; r < 4; ++r) {
                float cv = acc[ct][r] / fmaxf(na[r] * nb[ct], EPS);
                rowm[r] = fmaxf(rowm[r], cv);
                colm[ct] = fmaxf(colm[ct], cv);
            }
        }

#pragma unroll
        for (int r = 0; r < 4; ++r) {
            float v = rowm[r];
            v = fmaxf(v, __shfl_xor(v, 1, 64));
            v = fmaxf(v, __shfl_xor(v, 2, 64));
            v = fmaxf(v, __shfl_xor(v, 4, 64));
            v = fmaxf(v, __shfl_xor(v, 8, 64));
            rowm[r] = v;
        }
        if (c == 0) {
#pragma unroll
            for (int r = 0; r < 4; ++r) {
                int i = m0 + q * 4 + r;
                out[(b * SS + i) * 160 + dir * 80 + 20 + l] = rowm[r];
            }
        }

#pragma unroll
        for (int ct = 0; ct < 4; ++ct) {
            float v = colm[ct];
            v = fmaxf(v, __shfl_xor(v, 16, 64));
            v = fmaxf(v, __shfl_xor(v, 32, 64));
            colm[ct] = v;
        }
        if (q == 0) {
#pragma unroll
            for (int ct = 0; ct < 4; ++ct) cmL[wv_ * 64 + ct * 16 + c] = colm[ct];
        }
        __syncthreads();
        if (t < 64) {
            float m = fmaxf(fmaxf(cmL[t], cmL[64 + t]), fmaxf(cmL[128 + t], cmL[192 + t]));
            out[BB * SS * 160 + (b * SS + t) * 160 + dir * 80 + 20 + l] = m;
        }
    }
}

extern "C" void kernel_launch(void* const* d_in, const int* in_sizes, int n_in,
                              void* d_out, int out_size, void* d_ws, size_t ws_size,
                              hipStream_t stream) {
    const float* conp = (const float*)d_in[0];
    const float* conh = (const float*)d_in[1];
    const float* w1 = (const float*)d_in[2];
    const float* w2 = (const float*)d_in[3];
    const float* w3 = (const float*)d_in[4];
    const float* w4 = (const float*)d_in[5];
    const float* w5 = (const float*)d_in[6];
    const float* w6 = (const float*)d_in[7];
    const float* w7 = (const float*)d_in[8];
    const float* w8 = (const float*)d_in[9];
    float* out = (float*)d_out;
    float* ws  = (float*)d_ws;

    float* wn     = ws;                        // 163840
    float* meanv  = wn + 4 * BB * SS * LL;     // 1638400
    float* maxv   = meanv + 4 * BB * SS * HH;  // 1638400

    fused1_kernel<<<512, 512, 0, stream>>>(conp, conh, w3, w4, wn, meanv, maxv);
    fused2_kernel<<<2048, 256, 0, stream>>>(conp, conh, meanv, maxv,
                                            w1, w2, w3, w4, w5, w6, w7, w8, wn, out);
}